// Round 3
// baseline (1976.243 us; speedup 1.0000x reference)
//
#include <hip/hip_runtime.h>
#include <stdint.h>

#define L_LAYERS 4
#define BATCH 8
#define PHH 24
#define PWW 24
#define PP (PHH*PWW)        // 576
#define DD 1024
#define ROWS (BATCH*PP)     // 4608
#define OH 336
#define OW 336
#define NTILES 72           // 4608/64  (64-col max groups)
#define NCOMBO 12           // 3 radii x 4 layers
// 256x256 tiling for the pipelined GEMM
#define TT2 18              // 4608/256
#define NPAIRS2 (TT2*(TT2+1)/2)   // 171 upper-triangle tiles
#define TOTBLK2 (NPAIRS2*NCOMBO)  // 2052
#define XQ (TOTBLK2/8)      // 256
#define XR (TOTBLK2%8)      // 4
#define PRESCALE 1024.0f    // fp8 quant prescale (power of 2, exact)
#define INV_PRESCALE2_X2 (1.f/524288.f)   // 2 / PRESCALE^2

typedef __attribute__((ext_vector_type(8))) int i32x8;
typedef __attribute__((ext_vector_type(4))) float f32x4;

// float -> bf16 round-to-nearest-even (raw bits)
__device__ __forceinline__ unsigned int f2bf(float f) {
  unsigned int u = __float_as_uint(f);
  return (u + 0x7FFFu + ((u >> 16) & 1u)) >> 16;
}

__device__ __forceinline__ float bflo(unsigned int w) {
  return __uint_as_float(w << 16);
}
__device__ __forceinline__ float bfhi(unsigned int w) {
  return __uint_as_float(w & 0xFFFF0000u);
}

// expand 4 bf16 (8 bytes) to 4 floats
__device__ __forceinline__ void load4bf(float* d, const unsigned short* p) {
  const uint2 u = *(const uint2*)p;
  d[0] = bflo(u.x); d[1] = bfhi(u.x);
  d[2] = bflo(u.y); d[3] = bfhi(u.y);
}

// async global->LDS, 16B per lane. LDS dest is wave-uniform base + lane*16
// (base = first ACTIVE lane) -> never predicate individual lanes off.
__device__ __forceinline__ void async16(const void* g, void* l) {
  __builtin_amdgcn_global_load_lds(
      (const __attribute__((address_space(1))) void*)(size_t)(uintptr_t)g,
      (__attribute__((address_space(3))) void*)(uint32_t)(uintptr_t)l,
      16, 0, 0);
}

// ---------------------------------------------------------------------------
// Kernel 1: sliding-window pool, BOTH axes (reads feat exactly once).
// ---------------------------------------------------------------------------
__global__ __launch_bounds__(256) void pool_kernel(
    const float* __restrict__ feat,      // [L][B][PP][DD]
    unsigned short* __restrict__ h3,     // [L][ROWS][DD] bf16 bits (3x3 sum)
    unsigned short* __restrict__ h5) {   // [L][ROWS][DD] bf16 bits (5x5 sum)
  const int dch = blockIdx.x;            // 64-dim chunk
  const int b = blockIdx.y;
  const int l = blockIdx.z >> 1;
  const int half = blockIdx.z & 1;
  const int py0 = half * 12, py1 = py0 + 11;
  const int t = threadIdx.x;
  const int pxg = t >> 5;                // 0..7
  const int d2 = t & 31;                 // float2 index within 64-dim chunk

  __shared__ float ring[5][24 * 64];     // 30 KB
  __shared__ unsigned int v3p[24 * 32];  // 3 KB packed bf16 pairs
  __shared__ unsigned int v5p[24 * 32];  // 3 KB

  const float* fb = feat + ((size_t)l * BATCH + b) * PP * DD + dch * 64 + d2 * 2;

  for (int yy = py0 - 2; yy <= py0 + 1; ++yy) {
    if (yy < 0) continue;
    #pragma unroll
    for (int i = 0; i < 3; ++i) {
      int px = i * 8 + pxg;
      *(float2*)&ring[yy % 5][px * 64 + d2 * 2] =
          *(const float2*)(fb + (size_t)(yy * PWW + px) * DD);
    }
  }
  for (int py = py0; py <= py1; ++py) {
    const int yl = py + 2;
    if (yl < PHH) {
      __syncthreads();
      #pragma unroll
      for (int i = 0; i < 3; ++i) {
        int px = i * 8 + pxg;
        *(float2*)&ring[yl % 5][px * 64 + d2 * 2] =
            *(const float2*)(fb + (size_t)(yl * PWW + px) * DD);
      }
    }
    __syncthreads();
    #pragma unroll
    for (int i = 0; i < 3; ++i) {
      int px = i * 8 + pxg;
      float s3x = 0.f, s3y = 0.f, s5x = 0.f, s5y = 0.f;
      #pragma unroll
      for (int dy = -2; dy <= 2; ++dy) {
        int yy = py + dy;
        if (yy < 0 || yy >= PHH) continue;
        float2 v = *(const float2*)&ring[yy % 5][px * 64 + d2 * 2];
        s5x += v.x; s5y += v.y;
        if (dy >= -1 && dy <= 1) { s3x += v.x; s3y += v.y; }
      }
      v3p[px * 32 + d2] = f2bf(s3x) | (f2bf(s3y) << 16);
      v5p[px * 32 + d2] = f2bf(s5x) | (f2bf(s5y) << 16);
    }
    __syncthreads();
    #pragma unroll
    for (int i = 0; i < 3; ++i) {
      int px = i * 8 + pxg;
      float h3x = 0.f, h3y = 0.f, h5x = 0.f, h5y = 0.f;
      #pragma unroll
      for (int dx = -2; dx <= 2; ++dx) {
        int xx = px + dx;
        if (xx < 0 || xx >= PWW) continue;
        unsigned int w5 = v5p[xx * 32 + d2];
        h5x += bflo(w5); h5y += bfhi(w5);
        if (dx >= -1 && dx <= 1) {
          unsigned int w3 = v3p[xx * 32 + d2];
          h3x += bflo(w3); h3y += bfhi(w3);
        }
      }
      const size_t idx =
          ((size_t)l * ROWS + b * PP + py * PWW + px) * DD + dch * 64 + d2 * 2;
      *(unsigned int*)&h3[idx] = f2bf(h3x) | (f2bf(h3y) << 16);
      *(unsigned int*)&h5[idx] = f2bf(h5x) | (f2bf(h5y) << 16);
    }
  }
}

// ---------------------------------------------------------------------------
// Kernel 2: normalize + fp8(e4m3) quantize (x PRESCALE).
// ---------------------------------------------------------------------------
__global__ __launch_bounds__(256) void quant_kernel(
    const float* __restrict__ feat,
    const unsigned short* __restrict__ h3,
    const unsigned short* __restrict__ h5,
    unsigned char* __restrict__ nf_all) {    // [NCOMBO][ROWS][DD] fp8
  const int row = blockIdx.x;
  const int l = blockIdx.y;
  const int t = threadIdx.x;
  const int lane = t & 63, w = t >> 6;
  const int d0 = t * 4;
  const size_t lro = ((size_t)l * ROWS + row) * DD + d0;

  float s1[4], s3[4], s5[4];
  {
    const float4 f = *(const float4*)(feat + lro);
    s1[0] = f.x; s1[1] = f.y; s1[2] = f.z; s1[3] = f.w;
  }
  load4bf(s3, h3 + lro);
  load4bf(s5, h5 + lro);

  float q1 = 0.f, q3 = 0.f, q5 = 0.f;
  #pragma unroll
  for (int j = 0; j < 4; ++j) {
    q1 += s1[j]*s1[j]; q3 += s3[j]*s3[j]; q5 += s5[j]*s5[j];
  }
  #pragma unroll
  for (int off = 32; off > 0; off >>= 1) {
    q1 += __shfl_down(q1, off);
    q3 += __shfl_down(q3, off);
    q5 += __shfl_down(q5, off);
  }
  __shared__ float red[4][3];
  if (lane == 0) { red[w][0] = q1; red[w][1] = q3; red[w][2] = q5; }
  __syncthreads();
  const float rn1 = rsqrtf(red[0][0] + red[1][0] + red[2][0] + red[3][0]) * PRESCALE;
  const float rn3 = rsqrtf(red[0][1] + red[1][1] + red[2][1] + red[3][1]) * PRESCALE;
  const float rn5 = rsqrtf(red[0][2] + red[1][2] + red[2][2] + red[3][2]) * PRESCALE;

  const size_t ro = (size_t)row * DD + d0;
  unsigned int o;
  o = __builtin_amdgcn_cvt_pk_fp8_f32(s1[0]*rn1, s1[1]*rn1, 0, false);
  o = __builtin_amdgcn_cvt_pk_fp8_f32(s1[2]*rn1, s1[3]*rn1, o, true);
  *(unsigned int*)(nf_all + (size_t)(0*L_LAYERS + l) * ROWS * DD + ro) = o;
  o = __builtin_amdgcn_cvt_pk_fp8_f32(s3[0]*rn3, s3[1]*rn3, 0, false);
  o = __builtin_amdgcn_cvt_pk_fp8_f32(s3[2]*rn3, s3[3]*rn3, o, true);
  *(unsigned int*)(nf_all + (size_t)(1*L_LAYERS + l) * ROWS * DD + ro) = o;
  o = __builtin_amdgcn_cvt_pk_fp8_f32(s5[0]*rn5, s5[1]*rn5, 0, false);
  o = __builtin_amdgcn_cvt_pk_fp8_f32(s5[2]*rn5, s5[3]*rn5, o, true);
  *(unsigned int*)(nf_all + (size_t)(2*L_LAYERS + l) * ROWS * DD + ro) = o;
}

// ---------------------------------------------------------------------------
// Kernel 3: symmetric Gram GEMM, MX-fp8, 256x256 tile, 8 waves (4m x 2n),
// double-buffered LDS as four named arrays, one __syncthreads per K-tile.
//
// Round-1/2 post-mortem: __launch_bounds__(512, 2) capped the allocator at
// 128 VGPR/wave (VGPR_Count=128 exactly, both rounds) -> the 128-dword
// accumulator ate the whole file, operands spilled every phase -> 2.2 GB
// scratch WRITE_SIZE, 3.2 GB FETCH, MfmaUtil 2.8%. The 128 KB LDS already
// limits residency to 1 workgroup/CU, so the min-occupancy arg bought
// nothing. Fix: __launch_bounds__(512) -> 256-reg cap -> acc in AGPRs,
// arch ~100 regs, no spill. Everything else byte-identical to round 2
// (correctness verified twice, absmax 0.0078125).
// ---------------------------------------------------------------------------
__device__ __forceinline__ void gemm_step(
    const unsigned char* Acur, const unsigned char* Bcur,   // LDS read base + frag offset
    unsigned char* Anext, unsigned char* Bnext,             // LDS stage dest base + t*16
    const unsigned char* gAn, const unsigned char* gBn,     // per-lane global src (next tile)
    bool doStage, f32x4 (&acc)[4][8]) {
  // issue A prefetch first (maximal lead time)
  if (doStage) {
    #pragma unroll
    for (int i = 0; i < 4; ++i) async16(gAn + i * 65536, Anext + i * 8192);
  }
  __builtin_amdgcn_sched_barrier(0);
  const i32x8 a0 = *(const i32x8*)(Acur +    0);
  const i32x8 a1 = *(const i32x8*)(Acur + 2048);
  const i32x8 a2 = *(const i32x8*)(Acur + 4096);
  const i32x8 a3 = *(const i32x8*)(Acur + 6144);
  #pragma unroll
  for (int n = 0; n < 4; ++n) {
    const i32x8 b = *(const i32x8*)(Bcur + n * 2048);
    acc[0][n] = __builtin_amdgcn_mfma_scale_f32_16x16x128_f8f6f4(a0, b, acc[0][n], 0, 0, 0, 0x7F7F7F7F, 0, 0x7F7F7F7F);
    acc[1][n] = __builtin_amdgcn_mfma_scale_f32_16x16x128_f8f6f4(a1, b, acc[1][n], 0, 0, 0, 0x7F7F7F7F, 0, 0x7F7F7F7F);
    acc[2][n] = __builtin_amdgcn_mfma_scale_f32_16x16x128_f8f6f4(a2, b, acc[2][n], 0, 0, 0, 0x7F7F7F7F, 0, 0x7F7F7F7F);
    acc[3][n] = __builtin_amdgcn_mfma_scale_f32_16x16x128_f8f6f4(a3, b, acc[3][n], 0, 0, 0, 0x7F7F7F7F, 0, 0x7F7F7F7F);
  }
  // liveness fence: b0..b3 dead here; b4..b7 not yet hoisted
  __builtin_amdgcn_sched_barrier(0);
  if (doStage) {
    #pragma unroll
    for (int i = 0; i < 4; ++i) async16(gBn + i * 65536, Bnext + i * 8192);
  }
  #pragma unroll
  for (int n = 4; n < 8; ++n) {
    const i32x8 b = *(const i32x8*)(Bcur + n * 2048);
    acc[0][n] = __builtin_amdgcn_mfma_scale_f32_16x16x128_f8f6f4(a0, b, acc[0][n], 0, 0, 0, 0x7F7F7F7F, 0, 0x7F7F7F7F);
    acc[1][n] = __builtin_amdgcn_mfma_scale_f32_16x16x128_f8f6f4(a1, b, acc[1][n], 0, 0, 0, 0x7F7F7F7F, 0, 0x7F7F7F7F);
    acc[2][n] = __builtin_amdgcn_mfma_scale_f32_16x16x128_f8f6f4(a2, b, acc[2][n], 0, 0, 0, 0x7F7F7F7F, 0, 0x7F7F7F7F);
    acc[3][n] = __builtin_amdgcn_mfma_scale_f32_16x16x128_f8f6f4(a3, b, acc[3][n], 0, 0, 0, 0x7F7F7F7F, 0, 0x7F7F7F7F);
  }
  // one full drain per K-tile: prefetch has had 16-32 MFMAs in flight
  __syncthreads();
}

__global__ __launch_bounds__(512) void gemm_max_kernel(
    const unsigned char* __restrict__ nf_all,   // [NCOMBO][ROWS][DD] fp8
    float* __restrict__ part) {                 // [NCOMBO][ROWS][NTILES]
  // bijective XCD-aware swizzle (TOTBLK2 % 8 != 0 -> m204 form)
  const int bid = blockIdx.x;
  const int xcd = bid & 7;
  const int slot = (xcd < XR ? xcd * (XQ + 1) : XR * (XQ + 1) + (xcd - XR) * XQ)
                   + (bid >> 3);
  const int combo = slot / NPAIRS2;
  int rem = slot % NPAIRS2;
  int it = 0;
  while (rem >= TT2 - it) { rem -= TT2 - it; ++it; }
  const int jt = it + rem;
  const int row0 = it * 256;
  const int col0 = jt * 256;

  // dead-tile check: both tiles fully inside the same image -> never read
  {
    const bool inA = (row0 / PP) == ((row0 + 255) / PP);
    const bool inB = (col0 / PP) == ((col0 + 255) / PP);
    if (inA && inB && (row0 / PP) == (col0 / PP)) return;
  }

  __shared__ unsigned char A0[256 * 128];   // 32 KB each, 128 KB total
  __shared__ unsigned char A1[256 * 128];
  __shared__ unsigned char B0[256 * 128];
  __shared__ unsigned char B1[256 * 128];

  const int t = threadIdx.x;
  const int lane = t & 63;
  const int wave = t >> 6;       // 0..7
  const int wm = wave >> 1;      // 0..3 : 64-row slice
  const int wn = wave & 1;       // 0..1 : 128-col slice

  const unsigned char* nf = nf_all + (size_t)combo * ROWS * DD;
  float* partialL = part + (size_t)combo * ROWS * NTILES;

  const f32x4 zero = {0.f, 0.f, 0.f, 0.f};
  f32x4 acc[4][8];
  #pragma unroll
  for (int m = 0; m < 4; ++m)
    #pragma unroll
    for (int n = 0; n < 8; ++n) acc[m][n] = zero;

  // staging: chunk i (i=0..3), this thread handles 16B-chunk c = i*512+t:
  //   row = i*64 + (t>>3), slot j = t&7, global granule g = j ^ (row&6).
  // Since (i*64+r)&6 == r&6, ONE per-lane base covers all chunks:
  const int r = t >> 3;
  const int gg = (t & 7) ^ (r & 6);
  const unsigned char* gAs = nf + (size_t)row0 * DD + (size_t)r * DD + gg * 16;
  const unsigned char* gBs = nf + (size_t)col0 * DD + (size_t)r * DD + gg * 16;
  const int ldst = t * 16;       // LDS dest base offset (+ i*8192 per chunk)

  // lane-constant LDS fragment offset: 32B granule (2q) ^ (r15 & 6)
  const int r15 = lane & 15;
  const int loff = ((((lane >> 4) << 1) ^ (r15 & 6)) << 4);
  const int aRowOff = (wm * 64 + r15) * 128 + loff;
  const int bRowOff = (wn * 128 + r15) * 128 + loff;

  // prologue: stage K-tile 0 into A0/B0, full drain
  #pragma unroll
  for (int i = 0; i < 4; ++i) async16(gAs + i * 65536, &A0[ldst + i * 8192]);
  #pragma unroll
  for (int i = 0; i < 4; ++i) async16(gBs + i * 65536, &B0[ldst + i * 8192]);
  __syncthreads();

  // main loop: 8 K-tiles, unrolled x2 over named buffers
  #pragma unroll
  for (int kk = 0; kk < 4; ++kk) {
    // even tile 2kk: compute A0/B0, prefetch tile 2kk+1 -> A1/B1
    gemm_step(A0 + aRowOff, B0 + bRowOff, &A1[ldst], &B1[ldst],
              gAs + (2 * kk + 1) * 128, gBs + (2 * kk + 1) * 128,
              true, acc);
    // odd tile 2kk+1: compute A1/B1, prefetch tile 2kk+2 -> A0/B0
    gemm_step(A1 + aRowOff, B1 + bRowOff, &A0[ldst], &B0[ldst],
              gAs + (2 * kk + 2) * 128, gBs + (2 * kk + 2) * 128,
              kk < 3, acc);
  }

  // C/D layout: col = lane&15, row = (lane>>4)*4 + reg (shape-determined)
  // Row-max per 64-col group: this wave's 128 cols = groups jt*4+wn*2+{0,1}.
  #pragma unroll
  for (int m = 0; m < 4; ++m) {
    #pragma unroll
    for (int g = 0; g < 4; ++g) {
      #pragma unroll
      for (int h = 0; h < 2; ++h) {
        float v = fmaxf(fmaxf(acc[m][4*h+0][g], acc[m][4*h+1][g]),
                        fmaxf(acc[m][4*h+2][g], acc[m][4*h+3][g]));
        v = fmaxf(v, __shfl_xor(v, 1));
        v = fmaxf(v, __shfl_xor(v, 2));
        v = fmaxf(v, __shfl_xor(v, 4));
        v = fmaxf(v, __shfl_xor(v, 8));
        if ((lane & 15) == 0) {
          int row = row0 + wm * 64 + m * 16 + (lane >> 4) * 4 + g;
          partialL[(size_t)row * NTILES + jt * 4 + wn * 2 + h] = v;
        }
      }
    }
  }
  // Col-max over this wave's 64 rows (64-row group it*4+wm), transposed.
  if (it != jt) {
    #pragma unroll
    for (int n = 0; n < 8; ++n) {
      float v = -1e30f;
      #pragma unroll
      for (int m = 0; m < 4; ++m)
        #pragma unroll
        for (int g = 0; g < 4; ++g) v = fmaxf(v, acc[m][n][g]);
      v = fmaxf(v, __shfl_xor(v, 16));
      v = fmaxf(v, __shfl_xor(v, 32));
      if (lane < 16) {
        int col = col0 + wn * 128 + n * 16 + lane;
        partialL[(size_t)col * NTILES + it * 4 + wm] = v;
      }
    }
  }
}

// ---------------------------------------------------------------------------
// Kernel 4: per row: for each of 12 combos, max over 9 q-groups per image c,
// d-transform (undo fp8 prescale), top-2 smallest over c != b; sum -> scores.
// ---------------------------------------------------------------------------
__global__ __launch_bounds__(256) void reduce_topk_kernel(
    const float* __restrict__ part,      // [NCOMBO][ROWS][NTILES]
    float* __restrict__ scores) {        // [ROWS]
  const int row = blockIdx.x * 256 + threadIdx.x;
  if (row >= ROWS) return;
  const int b = row / PP;
  float sum = 0.f;
  for (int k = 0; k < NCOMBO; ++k) {
    const float* pr = part + ((size_t)k * ROWS + row) * NTILES;
    float d1 = 1e30f, d2 = 1e30f;
    #pragma unroll
    for (int c = 0; c < BATCH; ++c) {
      if (c == b) continue;
      float md = pr[c * 9];
      #pragma unroll
      for (int q = 1; q < 9; ++q) md = fmaxf(md, pr[c * 9 + q]);
      float d = sqrtf(fmaxf(2.f - md * INV_PRESCALE2_X2, 0.f));
      if (d < d1) { d2 = d1; d1 = d; }
      else if (d < d2) { d2 = d; }
    }
    sum += 0.5f * (d1 + d2);
  }
  scores[row] = sum;
}

// ---------------------------------------------------------------------------
// Kernel 5 (fused): blocks 0..3527 = bilinear (align_corners) 24x24 -> 336x336
// scaled 1/12; blocks 3528..3535 = scores_image[b] = max_p scores[b,p] / 12.
// ---------------------------------------------------------------------------
__global__ __launch_bounds__(256) void final_kernel(
    const float* __restrict__ scores, float* __restrict__ out) {
  const int bid = blockIdx.x;
  const int t = threadIdx.x;
  if (bid < (BATCH * OH * OW) / 256) {
    const int idx = bid * 256 + t;
    const int b = idx / (OH * OW);
    const int rem = idx % (OH * OW);
    const int y = rem / OW, x = rem % OW;
    const float sc = (float)(23.0 / 335.0);
    const float ys = y * sc, xs = x * sc;
    const int y0 = (int)floorf(ys), x0 = (int)floorf(xs);
    const float wy = ys - (float)y0, wx = xs - (float)x0;
    const int y1 = min(y0 + 1, PHH - 1), x1 = min(x0 + 1, PWW - 1);
    const float* sb = scores + b * PP;
    const float f00 = sb[y0 * PWW + x0], f01 = sb[y0 * PWW + x1];
    const float f10 = sb[y1 * PWW + x0], f11 = sb[y1 * PWW + x1];
    const float v = f00 * (1.f - wy) * (1.f - wx) + f01 * (1.f - wy) * wx +
                    f10 * wy * (1.f - wx) + f11 * wy * wx;
    out[8 + idx] = v * (1.f / 12.f);
  } else {
    const int b = bid - (BATCH * OH * OW) / 256;
    float m = -1e30f;
    for (int p = t; p < PP; p += 256) m = fmaxf(m, scores[b * PP + p]);
    #pragma unroll
    for (int off = 32; off > 0; off >>= 1) m = fmaxf(m, __shfl_down(m, off));
    __shared__ float red[4];
    if ((t & 63) == 0) red[t >> 6] = m;
    __syncthreads();
    if (t == 0)
      out[b] = fmaxf(fmaxf(red[0], red[1]), fmaxf(red[2], red[3])) * (1.f / 12.f);
  }
}

// ---------------------------------------------------------------------------
extern "C" void kernel_launch(void* const* d_in, const int* in_sizes, int n_in,
                              void* d_out, int out_size, void* d_ws, size_t ws_size,
                              hipStream_t stream) {
  const float* feat = (const float*)d_in[0];     // [4][8][576][1024] f32
  float* out = (float*)d_out;                    // [8] ++ [8][336][336]
  char* ws = (char*)d_ws;

  // workspace layout (~148 MB of ~302 MB)
  const size_t NF_BYTES   = (size_t)NCOMBO * ROWS * DD;            // 56,623,104 (fp8)
  const size_t PART_BYTES = (size_t)NCOMBO * ROWS * NTILES * 4;    // 15,925,248
  const size_t SCR_BYTES  = (size_t)ROWS * 4;                      //     18,432
  const size_t H_BYTES    = (size_t)L_LAYERS * ROWS * DD * 2;      // 37,748,736
  unsigned char*  nf_all = (unsigned char*)ws;
  float*          part   = (float*)(ws + NF_BYTES);
  float*          scr    = (float*)(ws + NF_BYTES + PART_BYTES);
  unsigned short* h3     = (unsigned short*)(ws + NF_BYTES + PART_BYTES + SCR_BYTES);
  unsigned short* h5     = (unsigned short*)(ws + NF_BYTES + PART_BYTES + SCR_BYTES + H_BYTES);

  pool_kernel<<<dim3(16, BATCH, L_LAYERS * 2), 256, 0, stream>>>(feat, h3, h5);
  quant_kernel<<<dim3(ROWS, L_LAYERS), 256, 0, stream>>>(feat, h3, h5, nf_all);
  gemm_max_kernel<<<TOTBLK2, 512, 0, stream>>>(nf_all, part);
  reduce_topk_kernel<<<(ROWS + 255) / 256, 256, 0, stream>>>(part, scr);
  final_kernel<<<(BATCH * OH * OW) / 256 + BATCH, 256, 0, stream>>>(scr, out);
}

// Round 4
// 346.074 us; speedup vs baseline: 5.7105x; 5.7105x over previous
//
#include <hip/hip_runtime.h>
#include <stdint.h>

#define L_LAYERS 4
#define BATCH 8
#define PHH 24
#define PWW 24
#define PP (PHH*PWW)        // 576
#define DD 1024
#define ROWS (BATCH*PP)     // 4608
#define OH 336
#define OW 336
#define NTILES 72           // 4608/64  (64-col max groups)
#define TT 36               // 4608/128 (128x128 tiles per dim)
#define NPAIRS (TT*(TT+1)/2)  // 666 upper-triangle tiles
#define NCOMBO 12           // 3 radii x 4 layers
#define TOTBLK (NPAIRS*NCOMBO)   // 7992 = 8 * 999
#define PRESCALE 1024.0f    // fp8 quant prescale (power of 2, exact)
#define INV_PRESCALE2_X2 (1.f/524288.f)   // 2 / PRESCALE^2

typedef __attribute__((ext_vector_type(8))) int i32x8;
typedef __attribute__((ext_vector_type(4))) float f32x4;

// float -> bf16 round-to-nearest-even (raw bits)
__device__ __forceinline__ unsigned int f2bf(float f) {
  unsigned int u = __float_as_uint(f);
  return (u + 0x7FFFu + ((u >> 16) & 1u)) >> 16;
}

__device__ __forceinline__ float bflo(unsigned int w) {
  return __uint_as_float(w << 16);
}
__device__ __forceinline__ float bfhi(unsigned int w) {
  return __uint_as_float(w & 0xFFFF0000u);
}

// expand 4 bf16 (8 bytes) to 4 floats
__device__ __forceinline__ void load4bf(float* d, const unsigned short* p) {
  const uint2 u = *(const uint2*)p;
  d[0] = bflo(u.x); d[1] = bfhi(u.x);
  d[2] = bflo(u.y); d[3] = bfhi(u.y);
}

// async global->LDS, 16B per lane. LDS dest is wave-uniform base + lane*16
// (base = first ACTIVE lane) -> never predicate individual lanes off.
__device__ __forceinline__ void async16(const void* g, void* l) {
  __builtin_amdgcn_global_load_lds(
      (const __attribute__((address_space(1))) void*)(size_t)(uintptr_t)g,
      (__attribute__((address_space(3))) void*)(uint32_t)(uintptr_t)l,
      16, 0, 0);
}

// ---------------------------------------------------------------------------
// Kernel 1: sliding-window pool, BOTH axes (reads feat exactly once).
// ---------------------------------------------------------------------------
__global__ __launch_bounds__(256) void pool_kernel(
    const float* __restrict__ feat,      // [L][B][PP][DD]
    unsigned short* __restrict__ h3,     // [L][ROWS][DD] bf16 bits (3x3 sum)
    unsigned short* __restrict__ h5) {   // [L][ROWS][DD] bf16 bits (5x5 sum)
  const int dch = blockIdx.x;            // 64-dim chunk
  const int b = blockIdx.y;
  const int l = blockIdx.z >> 1;
  const int half = blockIdx.z & 1;
  const int py0 = half * 12, py1 = py0 + 11;
  const int t = threadIdx.x;
  const int pxg = t >> 5;                // 0..7
  const int d2 = t & 31;                 // float2 index within 64-dim chunk

  __shared__ float ring[5][24 * 64];     // 30 KB
  __shared__ unsigned int v3p[24 * 32];  // 3 KB packed bf16 pairs
  __shared__ unsigned int v5p[24 * 32];  // 3 KB

  const float* fb = feat + ((size_t)l * BATCH + b) * PP * DD + dch * 64 + d2 * 2;

  for (int yy = py0 - 2; yy <= py0 + 1; ++yy) {
    if (yy < 0) continue;
    #pragma unroll
    for (int i = 0; i < 3; ++i) {
      int px = i * 8 + pxg;
      *(float2*)&ring[yy % 5][px * 64 + d2 * 2] =
          *(const float2*)(fb + (size_t)(yy * PWW + px) * DD);
    }
  }
  for (int py = py0; py <= py1; ++py) {
    const int yl = py + 2;
    if (yl < PHH) {
      __syncthreads();
      #pragma unroll
      for (int i = 0; i < 3; ++i) {
        int px = i * 8 + pxg;
        *(float2*)&ring[yl % 5][px * 64 + d2 * 2] =
            *(const float2*)(fb + (size_t)(yl * PWW + px) * DD);
      }
    }
    __syncthreads();
    #pragma unroll
    for (int i = 0; i < 3; ++i) {
      int px = i * 8 + pxg;
      float s3x = 0.f, s3y = 0.f, s5x = 0.f, s5y = 0.f;
      #pragma unroll
      for (int dy = -2; dy <= 2; ++dy) {
        int yy = py + dy;
        if (yy < 0 || yy >= PHH) continue;
        float2 v = *(const float2*)&ring[yy % 5][px * 64 + d2 * 2];
        s5x += v.x; s5y += v.y;
        if (dy >= -1 && dy <= 1) { s3x += v.x; s3y += v.y; }
      }
      v3p[px * 32 + d2] = f2bf(s3x) | (f2bf(s3y) << 16);
      v5p[px * 32 + d2] = f2bf(s5x) | (f2bf(s5y) << 16);
    }
    __syncthreads();
    #pragma unroll
    for (int i = 0; i < 3; ++i) {
      int px = i * 8 + pxg;
      float h3x = 0.f, h3y = 0.f, h5x = 0.f, h5y = 0.f;
      #pragma unroll
      for (int dx = -2; dx <= 2; ++dx) {
        int xx = px + dx;
        if (xx < 0 || xx >= PWW) continue;
        unsigned int w5 = v5p[xx * 32 + d2];
        h5x += bflo(w5); h5y += bfhi(w5);
        if (dx >= -1 && dx <= 1) {
          unsigned int w3 = v3p[xx * 32 + d2];
          h3x += bflo(w3); h3y += bfhi(w3);
        }
      }
      const size_t idx =
          ((size_t)l * ROWS + b * PP + py * PWW + px) * DD + dch * 64 + d2 * 2;
      *(unsigned int*)&h3[idx] = f2bf(h3x) | (f2bf(h3y) << 16);
      *(unsigned int*)&h5[idx] = f2bf(h5x) | (f2bf(h5y) << 16);
    }
  }
}

// ---------------------------------------------------------------------------
// Kernel 2: normalize + fp8(e4m3) quantize (x PRESCALE).
// ---------------------------------------------------------------------------
__global__ __launch_bounds__(256) void quant_kernel(
    const float* __restrict__ feat,
    const unsigned short* __restrict__ h3,
    const unsigned short* __restrict__ h5,
    unsigned char* __restrict__ nf_all) {    // [NCOMBO][ROWS][DD] fp8
  const int row = blockIdx.x;
  const int l = blockIdx.y;
  const int t = threadIdx.x;
  const int lane = t & 63, w = t >> 6;
  const int d0 = t * 4;
  const size_t lro = ((size_t)l * ROWS + row) * DD + d0;

  float s1[4], s3[4], s5[4];
  {
    const float4 f = *(const float4*)(feat + lro);
    s1[0] = f.x; s1[1] = f.y; s1[2] = f.z; s1[3] = f.w;
  }
  load4bf(s3, h3 + lro);
  load4bf(s5, h5 + lro);

  float q1 = 0.f, q3 = 0.f, q5 = 0.f;
  #pragma unroll
  for (int j = 0; j < 4; ++j) {
    q1 += s1[j]*s1[j]; q3 += s3[j]*s3[j]; q5 += s5[j]*s5[j];
  }
  #pragma unroll
  for (int off = 32; off > 0; off >>= 1) {
    q1 += __shfl_down(q1, off);
    q3 += __shfl_down(q3, off);
    q5 += __shfl_down(q5, off);
  }
  __shared__ float red[4][3];
  if (lane == 0) { red[w][0] = q1; red[w][1] = q3; red[w][2] = q5; }
  __syncthreads();
  const float rn1 = rsqrtf(red[0][0] + red[1][0] + red[2][0] + red[3][0]) * PRESCALE;
  const float rn3 = rsqrtf(red[0][1] + red[1][1] + red[2][1] + red[3][1]) * PRESCALE;
  const float rn5 = rsqrtf(red[0][2] + red[1][2] + red[2][2] + red[3][2]) * PRESCALE;

  const size_t ro = (size_t)row * DD + d0;
  unsigned int o;
  o = __builtin_amdgcn_cvt_pk_fp8_f32(s1[0]*rn1, s1[1]*rn1, 0, false);
  o = __builtin_amdgcn_cvt_pk_fp8_f32(s1[2]*rn1, s1[3]*rn1, o, true);
  *(unsigned int*)(nf_all + (size_t)(0*L_LAYERS + l) * ROWS * DD + ro) = o;
  o = __builtin_amdgcn_cvt_pk_fp8_f32(s3[0]*rn3, s3[1]*rn3, 0, false);
  o = __builtin_amdgcn_cvt_pk_fp8_f32(s3[2]*rn3, s3[3]*rn3, o, true);
  *(unsigned int*)(nf_all + (size_t)(1*L_LAYERS + l) * ROWS * DD + ro) = o;
  o = __builtin_amdgcn_cvt_pk_fp8_f32(s5[0]*rn5, s5[1]*rn5, 0, false);
  o = __builtin_amdgcn_cvt_pk_fp8_f32(s5[2]*rn5, s5[3]*rn5, o, true);
  *(unsigned int*)(nf_all + (size_t)(2*L_LAYERS + l) * ROWS * DD + ro) = o;
}

// ---------------------------------------------------------------------------
// Kernel 3: symmetric Gram GEMM, MX-fp8 (e4m3, unity E8M0 scales), K-tile=128.
// ROUND-0 VERIFIED VERSION (160 us, 84 VGPR, no scratch), restored.
//
// Session ledger on the 256x256/512-thread double-buffered variant
// (rounds 1-3, all FAILED identically): three structurally different
// encodings (runtime-indexed buffers + raw barriers / named buffers +
// sequential b-loads / no min-occupancy launch bound) all compiled to
// VGPR_Count=128 with ~516 dwords/thread scratch round-trip (2.2 GB
// WRITE_SIZE, 3.2 GB FETCH, MfmaUtil 2.8%, 1780 us). The 128-dword
// accumulator + 8-reg f8f6f4 operands at 512 threads consistently drives
// the allocator to spill, and this is not steerable from HIP source
// (launch-bounds change was a no-op on allocation). DO NOT retry that
// structure without offline asm inspection (-save-temps) showing the
// accumulator actually lands in AGPRs.
//
// This 128^2 structure: 1D grid + bijective XCD swizzle; upper-triangle
// 128x128 tiles; same-image pairs dead -> exit. 32B-granule XOR swizzle
// (j^(row&6)) -> each lane's 32 K-bytes contiguous+32B-aligned -> single
// i32x8 deref. NOTE: SQ_LDS_BANK_CONFLICT ~1.44e7 here is the
// staging-WRITE burst serialization of global_load_lds -- layout-
// independent, not a ds_read problem. Not a target.
// Fused row-max per 64-col group + col-max (transposed tile's row-max).
// ---------------------------------------------------------------------------
__global__ __launch_bounds__(256, 3) void gemm_max_kernel(
    const unsigned char* __restrict__ nf_all,   // [NCOMBO][ROWS][DD] fp8
    float* __restrict__ part) {                 // [NCOMBO][ROWS][NTILES]
  // XCD-aware swizzle (speed-only heuristic; every slot computed once)
  const int bid = blockIdx.x;
  const int slot = (bid & 7) * (TOTBLK / 8) + (bid >> 3);
  const int combo = slot / NPAIRS;
  int rem = slot % NPAIRS;
  int it = 0;
  while (rem >= TT - it) { rem -= TT - it; ++it; }
  const int jt = it + rem;
  const int row0 = it * 128;
  const int col0 = jt * 128;

  // dead-tile check: both tiles fully inside the same image -> never read
  {
    const bool inA = (row0 / PP) == ((row0 + 127) / PP);
    const bool inB = (col0 / PP) == ((col0 + 127) / PP);
    if (inA && inB && (row0 / PP) == (col0 / PP)) return;
  }

  __shared__ unsigned char As[128 * 128];
  __shared__ unsigned char Bs[128 * 128];

  const int t = threadIdx.x;
  const int lane = t & 63;
  const int wave = t >> 6;
  const int wm = wave >> 1;    // row half (64 rows)
  const int wn = wave & 1;     // col half (64 cols)

  const unsigned char* nf = nf_all + (size_t)combo * ROWS * DD;
  float* partialL = part + (size_t)combo * ROWS * NTILES;

  const f32x4 zero = {0.f, 0.f, 0.f, 0.f};
  f32x4 acc[4][4];
  #pragma unroll
  for (int m = 0; m < 4; ++m)
    #pragma unroll
    for (int n = 0; n < 4; ++n) acc[m][n] = zero;

  const unsigned char* gA = nf + (size_t)row0 * DD;
  const unsigned char* gB = nf + (size_t)col0 * DD;

  // lane-constant LDS fragment offset: 32B granule (2q) ^ (r15 & 6)
  const int r15 = lane & 15;
  const int loff = ((((lane >> 4) << 1) ^ (r15 & 6)) << 4);
  const unsigned char* Abase = As + (size_t)(wm * 64 + r15) * 128 + loff;
  const unsigned char* Bbase = Bs + (size_t)(wn * 64 + r15) * 128 + loff;

  for (int kt = 0; kt < DD / 128; ++kt) {
    const int k0 = kt * 128;
    // 128 rows x 128 B = 1024 16B-chunks per matrix; chunk c: row=c>>3,
    // slot j=c&7 holds global chunk j ^ (row&6)  (32B-granule XOR swizzle)
    #pragma unroll
    for (int i = 0; i < 4; ++i) {
      int c = i * 256 + t;
      int row = c >> 3, j = c & 7;
      int g = j ^ (row & 6);
      async16(gA + (size_t)row * DD + k0 + g * 16, &As[c * 16]);
    }
    #pragma unroll
    for (int i = 0; i < 4; ++i) {
      int c = i * 256 + t;
      int row = c >> 3, j = c & 7;
      int g = j ^ (row & 6);
      async16(gB + (size_t)row * DD + k0 + g * 16, &Bs[c * 16]);
    }
    __syncthreads();   // drains vmcnt (global_load_lds) + barrier

    const i32x8 a0 = *(const i32x8*)(Abase +    0);
    const i32x8 a1 = *(const i32x8*)(Abase + 2048);
    const i32x8 a2 = *(const i32x8*)(Abase + 4096);
    const i32x8 a3 = *(const i32x8*)(Abase + 6144);
    #pragma unroll
    for (int n = 0; n < 4; ++n) {
      const i32x8 bn = *(const i32x8*)(Bbase + n * 2048);
      acc[0][n] = __builtin_amdgcn_mfma_scale_f32_16x16x128_f8f6f4(
          a0, bn, acc[0][n], 0, 0, 0, 0x7F7F7F7F, 0, 0x7F7F7F7F);
      acc[1][n] = __builtin_amdgcn_mfma_scale_f32_16x16x128_f8f6f4(
          a1, bn, acc[1][n], 0, 0, 0, 0x7F7F7F7F, 0, 0x7F7F7F7F);
      acc[2][n] = __builtin_amdgcn_mfma_scale_f32_16x16x128_f8f6f4(
          a2, bn, acc[2][n], 0, 0, 0, 0x7F7F7F7F, 0, 0x7F7F7F7F);
      acc[3][n] = __builtin_amdgcn_mfma_scale_f32_16x16x128_f8f6f4(
          a3, bn, acc[3][n], 0, 0, 0, 0x7F7F7F7F, 0, 0x7F7F7F7F);
    }
    __syncthreads();
  }

  // C/D layout: col = lane&15, row = (lane>>4)*4 + reg (shape-determined)
  // Row-max over this wave's 64 cols (group 2*jt+wn).
  #pragma unroll
  for (int m = 0; m < 4; ++m) {
    #pragma unroll
    for (int g = 0; g < 4; ++g) {
      float v = fmaxf(fmaxf(acc[m][0][g], acc[m][1][g]),
                      fmaxf(acc[m][2][g], acc[m][3][g]));
      v = fmaxf(v, __shfl_xor(v, 1));
      v = fmaxf(v, __shfl_xor(v, 2));
      v = fmaxf(v, __shfl_xor(v, 4));
      v = fmaxf(v, __shfl_xor(v, 8));
      if ((lane & 15) == 0) {
        int row = row0 + wm * 64 + m * 16 + (lane >> 4) * 4 + g;
        partialL[(size_t)row * NTILES + 2 * jt + wn] = v;
      }
    }
  }
  // Col-max over this wave's 64 rows (group 2*it+wm), written transposed.
  if (it != jt) {
    #pragma unroll
    for (int n = 0; n < 4; ++n) {
      float v = -1e30f;
      #pragma unroll
      for (int m = 0; m < 4; ++m)
        #pragma unroll
        for (int g = 0; g < 4; ++g) v = fmaxf(v, acc[m][n][g]);
      v = fmaxf(v, __shfl_xor(v, 16));
      v = fmaxf(v, __shfl_xor(v, 32));
      if (lane < 16) {
        int col = col0 + wn * 64 + n * 16 + lane;
        partialL[(size_t)col * NTILES + 2 * it + wm] = v;
      }
    }
  }
}

// ---------------------------------------------------------------------------
// Kernel 4: per row: for each of 12 combos, max over 9 q-groups per image c,
// d-transform (undo fp8 prescale), top-2 smallest over c != b; sum -> scores.
// ---------------------------------------------------------------------------
__global__ __launch_bounds__(256) void reduce_topk_kernel(
    const float* __restrict__ part,      // [NCOMBO][ROWS][NTILES]
    float* __restrict__ scores) {        // [ROWS]
  const int row = blockIdx.x * 256 + threadIdx.x;
  if (row >= ROWS) return;
  const int b = row / PP;
  float sum = 0.f;
  for (int k = 0; k < NCOMBO; ++k) {
    const float* pr = part + ((size_t)k * ROWS + row) * NTILES;
    float d1 = 1e30f, d2 = 1e30f;
    #pragma unroll
    for (int c = 0; c < BATCH; ++c) {
      if (c == b) continue;
      float md = pr[c * 9];
      #pragma unroll
      for (int q = 1; q < 9; ++q) md = fmaxf(md, pr[c * 9 + q]);
      float d = sqrtf(fmaxf(2.f - md * INV_PRESCALE2_X2, 0.f));
      if (d < d1) { d2 = d1; d1 = d; }
      else if (d < d2) { d2 = d; }
    }
    sum += 0.5f * (d1 + d2);
  }
  scores[row] = sum;
}

// ---------------------------------------------------------------------------
// Kernel 5 (fused): blocks 0..3527 = bilinear (align_corners) 24x24 -> 336x336
// scaled 1/12; blocks 3528..3535 = scores_image[b] = max_p scores[b,p] / 12.
// ---------------------------------------------------------------------------
__global__ __launch_bounds__(256) void final_kernel(
    const float* __restrict__ scores, float* __restrict__ out) {
  const int bid = blockIdx.x;
  const int t = threadIdx.x;
  if (bid < (BATCH * OH * OW) / 256) {
    const int idx = bid * 256 + t;
    const int b = idx / (OH * OW);
    const int rem = idx % (OH * OW);
    const int y = rem / OW, x = rem % OW;
    const float sc = (float)(23.0 / 335.0);
    const float ys = y * sc, xs = x * sc;
    const int y0 = (int)floorf(ys), x0 = (int)floorf(xs);
    const float wy = ys - (float)y0, wx = xs - (float)x0;
    const int y1 = min(y0 + 1, PHH - 1), x1 = min(x0 + 1, PWW - 1);
    const float* sb = scores + b * PP;
    const float f00 = sb[y0 * PWW + x0], f01 = sb[y0 * PWW + x1];
    const float f10 = sb[y1 * PWW + x0], f11 = sb[y1 * PWW + x1];
    const float v = f00 * (1.f - wy) * (1.f - wx) + f01 * (1.f - wy) * wx +
                    f10 * wy * (1.f - wx) + f11 * wy * wx;
    out[8 + idx] = v * (1.f / 12.f);
  } else {
    const int b = bid - (BATCH * OH * OW) / 256;
    float m = -1e30f;
    for (int p = t; p < PP; p += 256) m = fmaxf(m, scores[b * PP + p]);
    #pragma unroll
    for (int off = 32; off > 0; off >>= 1) m = fmaxf(m, __shfl_down(m, off));
    __shared__ float red[4];
    if ((t & 63) == 0) red[t >> 6] = m;
    __syncthreads();
    if (t == 0)
      out[b] = fmaxf(fmaxf(red[0], red[1]), fmaxf(red[2], red[3])) * (1.f / 12.f);
  }
}

// ---------------------------------------------------------------------------
extern "C" void kernel_launch(void* const* d_in, const int* in_sizes, int n_in,
                              void* d_out, int out_size, void* d_ws, size_t ws_size,
                              hipStream_t stream) {
  const float* feat = (const float*)d_in[0];     // [4][8][576][1024] f32
  float* out = (float*)d_out;                    // [8] ++ [8][336][336]
  char* ws = (char*)d_ws;

  // workspace layout (~148 MB of ~302 MB)
  const size_t NF_BYTES   = (size_t)NCOMBO * ROWS * DD;            // 56,623,104 (fp8)
  const size_t PART_BYTES = (size_t)NCOMBO * ROWS * NTILES * 4;    // 15,925,248
  const size_t SCR_BYTES  = (size_t)ROWS * 4;                      //     18,432
  const size_t H_BYTES    = (size_t)L_LAYERS * ROWS * DD * 2;      // 37,748,736
  unsigned char*  nf_all = (unsigned char*)ws;
  float*          part   = (float*)(ws + NF_BYTES);
  float*          scr    = (float*)(ws + NF_BYTES + PART_BYTES);
  unsigned short* h3     = (unsigned short*)(ws + NF_BYTES + PART_BYTES + SCR_BYTES);
  unsigned short* h5     = (unsigned short*)(ws + NF_BYTES + PART_BYTES + SCR_BYTES + H_BYTES);

  pool_kernel<<<dim3(16, BATCH, L_LAYERS * 2), 256, 0, stream>>>(feat, h3, h5);
  quant_kernel<<<dim3(ROWS, L_LAYERS), 256, 0, stream>>>(feat, h3, h5, nf_all);
  gemm_max_kernel<<<TOTBLK, 256, 0, stream>>>(nf_all, part);
  reduce_topk_kernel<<<(ROWS + 255) / 256, 256, 0, stream>>>(part, scr);
  final_kernel<<<(BATCH * OH * OW) / 256 + BATCH, 256, 0, stream>>>(scr, out);
}

// Round 5
// 321.464 us; speedup vs baseline: 6.1476x; 1.0766x over previous
//
#include <hip/hip_runtime.h>
#include <stdint.h>

#define L_LAYERS 4
#define BATCH 8
#define PHH 24
#define PWW 24
#define PP (PHH*PWW)        // 576
#define DD 1024
#define ROWS (BATCH*PP)     // 4608
#define OH 336
#define OW 336
#define NTILES 72           // 4608/64  (64-col max groups)
#define TT 36               // 4608/128 (128x128 tiles per dim)
#define NPAIRS (TT*(TT+1)/2)  // 666 upper-triangle tiles
#define NCOMBO 12           // 3 radii x 4 layers
#define TOTBLK (NPAIRS*NCOMBO)   // 7992 = 8 * 999
#define PRESCALE 1024.0f    // fp8 quant prescale (power of 2, exact)
#define INV_PRESCALE2_X2 (1.f/524288.f)   // 2 / PRESCALE^2

typedef __attribute__((ext_vector_type(8))) int i32x8;
typedef __attribute__((ext_vector_type(4))) float f32x4;

// float -> bf16 round-to-nearest-even (raw bits)
__device__ __forceinline__ unsigned int f2bf(float f) {
  unsigned int u = __float_as_uint(f);
  return (u + 0x7FFFu + ((u >> 16) & 1u)) >> 16;
}

__device__ __forceinline__ float bflo(unsigned int w) {
  return __uint_as_float(w << 16);
}
__device__ __forceinline__ float bfhi(unsigned int w) {
  return __uint_as_float(w & 0xFFFF0000u);
}

// expand 4 bf16 (8 bytes) to 4 floats
__device__ __forceinline__ void load4bf(float* d, const unsigned short* p) {
  const uint2 u = *(const uint2*)p;
  d[0] = bflo(u.x); d[1] = bfhi(u.x);
  d[2] = bflo(u.y); d[3] = bfhi(u.y);
}

// async global->LDS, 16B per lane. LDS dest is wave-uniform base + lane*16
// (base = first ACTIVE lane) -> never predicate individual lanes off.
__device__ __forceinline__ void async16(const void* g, void* l) {
  __builtin_amdgcn_global_load_lds(
      (const __attribute__((address_space(1))) void*)(size_t)(uintptr_t)g,
      (__attribute__((address_space(3))) void*)(uint32_t)(uintptr_t)l,
      16, 0, 0);
}

// ---------------------------------------------------------------------------
// Kernel 1: sliding-window pool, BOTH axes (reads feat exactly once).
// v2 (round 5): vertical 5-row window kept in REGISTERS (named w0..w4,
// static indexing) instead of a 30 KB LDS ring -> no ring traffic and
// 2 barriers/iteration instead of 3. Only the horizontal exchange uses
// LDS (v3p/v5p packed bf16 rows). Summation order identical to v1
// (OOB rows are exact +0.f adds) -> bit-identical h3/h5.
// ---------------------------------------------------------------------------
__global__ __launch_bounds__(256) void pool_kernel(
    const float* __restrict__ feat,      // [L][B][PP][DD]
    unsigned short* __restrict__ h3,     // [L][ROWS][DD] bf16 bits (3x3 sum)
    unsigned short* __restrict__ h5) {   // [L][ROWS][DD] bf16 bits (5x5 sum)
  const int dch = blockIdx.x;            // 64-dim chunk
  const int b = blockIdx.y;
  const int l = blockIdx.z >> 1;
  const int half = blockIdx.z & 1;
  const int py0 = half * 12, py1 = py0 + 11;
  const int t = threadIdx.x;
  const int pxg = t >> 5;                // 0..7
  const int d2 = t & 31;                 // float2 index within 64-dim chunk

  __shared__ unsigned int v3p[24 * 32];  // 3 KB packed bf16 pairs
  __shared__ unsigned int v5p[24 * 32];  // 3 KB

  const float* fb = feat + ((size_t)l * BATCH + b) * PP * DD + dch * 64 + d2 * 2;

  const float2 z2 = {0.f, 0.f};
  // rolling window: w0..w4 = rows py-2 .. py+2 for this thread's 3 px
  float2 w0[3], w1[3], w2[3], w3[3], w4[3];
  #pragma unroll
  for (int i = 0; i < 3; ++i) { w0[i] = z2; w1[i] = z2; w2[i] = z2; w3[i] = z2; }

  // preload rows py0-2 .. py0+1 (OOB stays zero; conditions are block-uniform)
  if (py0 - 2 >= 0) {
    #pragma unroll
    for (int i = 0; i < 3; ++i) {
      int px = i * 8 + pxg;
      w0[i] = *(const float2*)(fb + (size_t)((py0 - 2) * PWW + px) * DD);
    }
  }
  if (py0 - 1 >= 0) {
    #pragma unroll
    for (int i = 0; i < 3; ++i) {
      int px = i * 8 + pxg;
      w1[i] = *(const float2*)(fb + (size_t)((py0 - 1) * PWW + px) * DD);
    }
  }
  #pragma unroll
  for (int i = 0; i < 3; ++i) {
    int px = i * 8 + pxg;
    w2[i] = *(const float2*)(fb + (size_t)(py0 * PWW + px) * DD);
    w3[i] = *(const float2*)(fb + (size_t)((py0 + 1) * PWW + px) * DD);
  }

  for (int py = py0; py <= py1; ++py) {
    // load row py+2 (block-uniform condition; zero when OOB)
    if (py + 2 < PHH) {
      #pragma unroll
      for (int i = 0; i < 3; ++i) {
        int px = i * 8 + pxg;
        w4[i] = *(const float2*)(fb + (size_t)((py + 2) * PWW + px) * DD);
      }
    } else {
      #pragma unroll
      for (int i = 0; i < 3; ++i) w4[i] = z2;
    }
    // vertical sums (same order as v1: dy=-1,0,1 and dy=-2..2) -> packed bf16
    #pragma unroll
    for (int i = 0; i < 3; ++i) {
      int px = i * 8 + pxg;
      float s3x = w1[i].x + w2[i].x + w3[i].x;
      float s3y = w1[i].y + w2[i].y + w3[i].y;
      float s5x = w0[i].x + w1[i].x + w2[i].x + w3[i].x + w4[i].x;
      float s5y = w0[i].y + w1[i].y + w2[i].y + w3[i].y + w4[i].y;
      v3p[px * 32 + d2] = f2bf(s3x) | (f2bf(s3y) << 16);
      v5p[px * 32 + d2] = f2bf(s5x) | (f2bf(s5y) << 16);
    }
    __syncthreads();     // v-rows visible
    // horizontal phase: 3/5-col windows over packed rows -> global h3/h5
    #pragma unroll
    for (int i = 0; i < 3; ++i) {
      int px = i * 8 + pxg;
      float h3x = 0.f, h3y = 0.f, h5x = 0.f, h5y = 0.f;
      #pragma unroll
      for (int dx = -2; dx <= 2; ++dx) {
        int xx = px + dx;
        if (xx < 0 || xx >= PWW) continue;
        unsigned int w5 = v5p[xx * 32 + d2];
        h5x += bflo(w5); h5y += bfhi(w5);
        if (dx >= -1 && dx <= 1) {
          unsigned int w3w = v3p[xx * 32 + d2];
          h3x += bflo(w3w); h3y += bfhi(w3w);
        }
      }
      const size_t idx =
          ((size_t)l * ROWS + b * PP + py * PWW + px) * DD + dch * 64 + d2 * 2;
      *(unsigned int*)&h3[idx] = f2bf(h3x) | (f2bf(h3y) << 16);
      *(unsigned int*)&h5[idx] = f2bf(h5x) | (f2bf(h5y) << 16);
    }
    __syncthreads();     // reads done before next iteration's v-writes
    // shift window (static indexing only)
    #pragma unroll
    for (int i = 0; i < 3; ++i) {
      w0[i] = w1[i]; w1[i] = w2[i]; w2[i] = w3[i]; w3[i] = w4[i];
    }
  }
}

// ---------------------------------------------------------------------------
// Kernel 2: normalize + fp8(e4m3) quantize (x PRESCALE).
// ---------------------------------------------------------------------------
__global__ __launch_bounds__(256) void quant_kernel(
    const float* __restrict__ feat,
    const unsigned short* __restrict__ h3,
    const unsigned short* __restrict__ h5,
    unsigned char* __restrict__ nf_all) {    // [NCOMBO][ROWS][DD] fp8
  const int row = blockIdx.x;
  const int l = blockIdx.y;
  const int t = threadIdx.x;
  const int lane = t & 63, w = t >> 6;
  const int d0 = t * 4;
  const size_t lro = ((size_t)l * ROWS + row) * DD + d0;

  float s1[4], s3[4], s5[4];
  {
    const float4 f = *(const float4*)(feat + lro);
    s1[0] = f.x; s1[1] = f.y; s1[2] = f.z; s1[3] = f.w;
  }
  load4bf(s3, h3 + lro);
  load4bf(s5, h5 + lro);

  float q1 = 0.f, q3 = 0.f, q5 = 0.f;
  #pragma unroll
  for (int j = 0; j < 4; ++j) {
    q1 += s1[j]*s1[j]; q3 += s3[j]*s3[j]; q5 += s5[j]*s5[j];
  }
  #pragma unroll
  for (int off = 32; off > 0; off >>= 1) {
    q1 += __shfl_down(q1, off);
    q3 += __shfl_down(q3, off);
    q5 += __shfl_down(q5, off);
  }
  __shared__ float red[4][3];
  if (lane == 0) { red[w][0] = q1; red[w][1] = q3; red[w][2] = q5; }
  __syncthreads();
  const float rn1 = rsqrtf(red[0][0] + red[1][0] + red[2][0] + red[3][0]) * PRESCALE;
  const float rn3 = rsqrtf(red[0][1] + red[1][1] + red[2][1] + red[3][1]) * PRESCALE;
  const float rn5 = rsqrtf(red[0][2] + red[1][2] + red[2][2] + red[3][2]) * PRESCALE;

  const size_t ro = (size_t)row * DD + d0;
  unsigned int o;
  o = __builtin_amdgcn_cvt_pk_fp8_f32(s1[0]*rn1, s1[1]*rn1, 0, false);
  o = __builtin_amdgcn_cvt_pk_fp8_f32(s1[2]*rn1, s1[3]*rn1, o, true);
  *(unsigned int*)(nf_all + (size_t)(0*L_LAYERS + l) * ROWS * DD + ro) = o;
  o = __builtin_amdgcn_cvt_pk_fp8_f32(s3[0]*rn3, s3[1]*rn3, 0, false);
  o = __builtin_amdgcn_cvt_pk_fp8_f32(s3[2]*rn3, s3[3]*rn3, o, true);
  *(unsigned int*)(nf_all + (size_t)(1*L_LAYERS + l) * ROWS * DD + ro) = o;
  o = __builtin_amdgcn_cvt_pk_fp8_f32(s5[0]*rn5, s5[1]*rn5, 0, false);
  o = __builtin_amdgcn_cvt_pk_fp8_f32(s5[2]*rn5, s5[3]*rn5, o, true);
  *(unsigned int*)(nf_all + (size_t)(2*L_LAYERS + l) * ROWS * DD + ro) = o;
}

// ---------------------------------------------------------------------------
// Kernel 3: symmetric Gram GEMM, MX-fp8 (e4m3, unity E8M0 scales), K-tile=128.
// ROUND-0 VERIFIED VERSION (160 us steady, 84 VGPR, no scratch). At 1.70 PF
// this meets/exceeds the m148 reference ceiling (1628 TF) for the
// 128^2-tile 2-barrier structure with MX-fp8 -> structurally maxed.
//
// Session ledger on the 256x256/512-thread double-buffered variant
// (rounds 1-3, all FAILED identically): three structurally different
// encodings (runtime-indexed buffers + raw barriers / named buffers +
// sequential b-loads / no min-occupancy launch bound) all compiled to
// VGPR_Count=128 with ~516 dwords/thread scratch round-trip (2.2 GB
// WRITE_SIZE, 3.2 GB FETCH, MfmaUtil 2.8%, 1780 us). DO NOT retry that
// structure without offline asm inspection (-save-temps) showing the
// accumulator actually lands in AGPRs.
// ---------------------------------------------------------------------------
__global__ __launch_bounds__(256, 3) void gemm_max_kernel(
    const unsigned char* __restrict__ nf_all,   // [NCOMBO][ROWS][DD] fp8
    float* __restrict__ part) {                 // [NCOMBO][ROWS][NTILES]
  // XCD-aware swizzle (speed-only heuristic; every slot computed once)
  const int bid = blockIdx.x;
  const int slot = (bid & 7) * (TOTBLK / 8) + (bid >> 3);
  const int combo = slot / NPAIRS;
  int rem = slot % NPAIRS;
  int it = 0;
  while (rem >= TT - it) { rem -= TT - it; ++it; }
  const int jt = it + rem;
  const int row0 = it * 128;
  const int col0 = jt * 128;

  // dead-tile check: both tiles fully inside the same image -> never read
  {
    const bool inA = (row0 / PP) == ((row0 + 127) / PP);
    const bool inB = (col0 / PP) == ((col0 + 127) / PP);
    if (inA && inB && (row0 / PP) == (col0 / PP)) return;
  }

  __shared__ unsigned char As[128 * 128];
  __shared__ unsigned char Bs[128 * 128];

  const int t = threadIdx.x;
  const int lane = t & 63;
  const int wave = t >> 6;
  const int wm = wave >> 1;    // row half (64 rows)
  const int wn = wave & 1;     // col half (64 cols)

  const unsigned char* nf = nf_all + (size_t)combo * ROWS * DD;
  float* partialL = part + (size_t)combo * ROWS * NTILES;

  const f32x4 zero = {0.f, 0.f, 0.f, 0.f};
  f32x4 acc[4][4];
  #pragma unroll
  for (int m = 0; m < 4; ++m)
    #pragma unroll
    for (int n = 0; n < 4; ++n) acc[m][n] = zero;

  const unsigned char* gA = nf + (size_t)row0 * DD;
  const unsigned char* gB = nf + (size_t)col0 * DD;

  // lane-constant LDS fragment offset: 32B granule (2q) ^ (r15 & 6)
  const int r15 = lane & 15;
  const int loff = ((((lane >> 4) << 1) ^ (r15 & 6)) << 4);
  const unsigned char* Abase = As + (size_t)(wm * 64 + r15) * 128 + loff;
  const unsigned char* Bbase = Bs + (size_t)(wn * 64 + r15) * 128 + loff;

  for (int kt = 0; kt < DD / 128; ++kt) {
    const int k0 = kt * 128;
    // 128 rows x 128 B = 1024 16B-chunks per matrix; chunk c: row=c>>3,
    // slot j=c&7 holds global chunk j ^ (row&6)  (32B-granule XOR swizzle)
    #pragma unroll
    for (int i = 0; i < 4; ++i) {
      int c = i * 256 + t;
      int row = c >> 3, j = c & 7;
      int g = j ^ (row & 6);
      async16(gA + (size_t)row * DD + k0 + g * 16, &As[c * 16]);
    }
    #pragma unroll
    for (int i = 0; i < 4; ++i) {
      int c = i * 256 + t;
      int row = c >> 3, j = c & 7;
      int g = j ^ (row & 6);
      async16(gB + (size_t)row * DD + k0 + g * 16, &Bs[c * 16]);
    }
    __syncthreads();   // drains vmcnt (global_load_lds) + barrier

    const i32x8 a0 = *(const i32x8*)(Abase +    0);
    const i32x8 a1 = *(const i32x8*)(Abase + 2048);
    const i32x8 a2 = *(const i32x8*)(Abase + 4096);
    const i32x8 a3 = *(const i32x8*)(Abase + 6144);
    #pragma unroll
    for (int n = 0; n < 4; ++n) {
      const i32x8 bn = *(const i32x8*)(Bbase + n * 2048);
      acc[0][n] = __builtin_amdgcn_mfma_scale_f32_16x16x128_f8f6f4(
          a0, bn, acc[0][n], 0, 0, 0, 0x7F7F7F7F, 0, 0x7F7F7F7F);
      acc[1][n] = __builtin_amdgcn_mfma_scale_f32_16x16x128_f8f6f4(
          a1, bn, acc[1][n], 0, 0, 0, 0x7F7F7F7F, 0, 0x7F7F7F7F);
      acc[2][n] = __builtin_amdgcn_mfma_scale_f32_16x16x128_f8f6f4(
          a2, bn, acc[2][n], 0, 0, 0, 0x7F7F7F7F, 0, 0x7F7F7F7F);
      acc[3][n] = __builtin_amdgcn_mfma_scale_f32_16x16x128_f8f6f4(
          a3, bn, acc[3][n], 0, 0, 0, 0x7F7F7F7F, 0, 0x7F7F7F7F);
    }
    __syncthreads();
  }

  // C/D layout: col = lane&15, row = (lane>>4)*4 + reg (shape-determined)
  // Row-max over this wave's 64 cols (group 2*jt+wn).
  #pragma unroll
  for (int m = 0; m < 4; ++m) {
    #pragma unroll
    for (int g = 0; g < 4; ++g) {
      float v = fmaxf(fmaxf(acc[m][0][g], acc[m][1][g]),
                      fmaxf(acc[m][2][g], acc[m][3][g]));
      v = fmaxf(v, __shfl_xor(v, 1));
      v = fmaxf(v, __shfl_xor(v, 2));
      v = fmaxf(v, __shfl_xor(v, 4));
      v = fmaxf(v, __shfl_xor(v, 8));
      if ((lane & 15) == 0) {
        int row = row0 + wm * 64 + m * 16 + (lane >> 4) * 4 + g;
        partialL[(size_t)row * NTILES + 2 * jt + wn] = v;
      }
    }
  }
  // Col-max over this wave's 64 rows (group 2*it+wm), written transposed.
  if (it != jt) {
    #pragma unroll
    for (int n = 0; n < 4; ++n) {
      float v = -1e30f;
      #pragma unroll
      for (int m = 0; m < 4; ++m)
        #pragma unroll
        for (int g = 0; g < 4; ++g) v = fmaxf(v, acc[m][n][g]);
      v = fmaxf(v, __shfl_xor(v, 16));
      v = fmaxf(v, __shfl_xor(v, 32));
      if (lane < 16) {
        int col = col0 + wn * 64 + n * 16 + lane;
        partialL[(size_t)col * NTILES + 2 * it + wm] = v;
      }
    }
  }
}

// ---------------------------------------------------------------------------
// Kernel 4 (round-5 split): per (row, combo): max over 9 q-groups per image,
// d-transform, top-2 smallest over c != b -> partial score. Grid (18, 12)
// instead of 18 blocks total (was 7% of the chip).
// ---------------------------------------------------------------------------
__global__ __launch_bounds__(256) void reduce_topk_kernel(
    const float* __restrict__ part,      // [NCOMBO][ROWS][NTILES]
    float* __restrict__ scores_k) {      // [NCOMBO][ROWS]
  const int row = blockIdx.x * 256 + threadIdx.x;
  if (row >= ROWS) return;
  const int k = blockIdx.y;
  const int b = row / PP;
  const float* pr = part + ((size_t)k * ROWS + row) * NTILES;
  float d1 = 1e30f, d2 = 1e30f;
  #pragma unroll
  for (int c = 0; c < BATCH; ++c) {
    if (c == b) continue;
    float md = pr[c * 9];
    #pragma unroll
    for (int q = 1; q < 9; ++q) md = fmaxf(md, pr[c * 9 + q]);
    float d = sqrtf(fmaxf(2.f - md * INV_PRESCALE2_X2, 0.f));
    if (d < d1) { d2 = d1; d1 = d; }
    else if (d < d2) { d2 = d; }
  }
  scores_k[(size_t)k * ROWS + row] = 0.5f * (d1 + d2);
}

// Sum the 12 combo partials in ORIGINAL k order (bit-identical to v1).
__global__ __launch_bounds__(256) void sum_scores_kernel(
    const float* __restrict__ scores_k,  // [NCOMBO][ROWS]
    float* __restrict__ scores) {        // [ROWS]
  const int row = blockIdx.x * 256 + threadIdx.x;
  if (row >= ROWS) return;
  float sum = 0.f;
  #pragma unroll
  for (int k = 0; k < NCOMBO; ++k) sum += scores_k[(size_t)k * ROWS + row];
  scores[row] = sum;
}

// ---------------------------------------------------------------------------
// Kernel 5 (fused): blocks 0..3527 = bilinear (align_corners) 24x24 -> 336x336
// scaled 1/12; blocks 3528..3535 = scores_image[b] = max_p scores[b,p] / 12.
// ---------------------------------------------------------------------------
__global__ __launch_bounds__(256) void final_kernel(
    const float* __restrict__ scores, float* __restrict__ out) {
  const int bid = blockIdx.x;
  const int t = threadIdx.x;
  if (bid < (BATCH * OH * OW) / 256) {
    const int idx = bid * 256 + t;
    const int b = idx / (OH * OW);
    const int rem = idx % (OH * OW);
    const int y = rem / OW, x = rem % OW;
    const float sc = (float)(23.0 / 335.0);
    const float ys = y * sc, xs = x * sc;
    const int y0 = (int)floorf(ys), x0 = (int)floorf(xs);
    const float wy = ys - (float)y0, wx = xs - (float)x0;
    const int y1 = min(y0 + 1, PHH - 1), x1 = min(x0 + 1, PWW - 1);
    const float* sb = scores + b * PP;
    const float f00 = sb[y0 * PWW + x0], f01 = sb[y0 * PWW + x1];
    const float f10 = sb[y1 * PWW + x0], f11 = sb[y1 * PWW + x1];
    const float v = f00 * (1.f - wy) * (1.f - wx) + f01 * (1.f - wy) * wx +
                    f10 * wy * (1.f - wx) + f11 * wy * wx;
    out[8 + idx] = v * (1.f / 12.f);
  } else {
    const int b = bid - (BATCH * OH * OW) / 256;
    float m = -1e30f;
    for (int p = t; p < PP; p += 256) m = fmaxf(m, scores[b * PP + p]);
    #pragma unroll
    for (int off = 32; off > 0; off >>= 1) m = fmaxf(m, __shfl_down(m, off));
    __shared__ float red[4];
    if ((t & 63) == 0) red[t >> 6] = m;
    __syncthreads();
    if (t == 0)
      out[b] = fmaxf(fmaxf(red[0], red[1]), fmaxf(red[2], red[3])) * (1.f / 12.f);
  }
}

// ---------------------------------------------------------------------------
extern "C" void kernel_launch(void* const* d_in, const int* in_sizes, int n_in,
                              void* d_out, int out_size, void* d_ws, size_t ws_size,
                              hipStream_t stream) {
  const float* feat = (const float*)d_in[0];     // [4][8][576][1024] f32
  float* out = (float*)d_out;                    // [8] ++ [8][336][336]
  char* ws = (char*)d_ws;

  // workspace layout (~148.4 MB of ~302 MB)
  const size_t NF_BYTES   = (size_t)NCOMBO * ROWS * DD;            // 56,623,104 (fp8)
  const size_t PART_BYTES = (size_t)NCOMBO * ROWS * NTILES * 4;    // 15,925,248
  const size_t SCR_BYTES  = (size_t)ROWS * 4;                      //     18,432
  const size_t SCRK_BYTES = (size_t)NCOMBO * ROWS * 4;             //    221,184
  const size_t H_BYTES    = (size_t)L_LAYERS * ROWS * DD * 2;      // 37,748,736
  unsigned char*  nf_all = (unsigned char*)ws;
  float*          part   = (float*)(ws + NF_BYTES);
  float*          scr    = (float*)(ws + NF_BYTES + PART_BYTES);
  float*          scrk   = (float*)(ws + NF_BYTES + PART_BYTES + SCR_BYTES);
  unsigned short* h3     = (unsigned short*)(ws + NF_BYTES + PART_BYTES + SCR_BYTES + SCRK_BYTES);
  unsigned short* h5     = (unsigned short*)(ws + NF_BYTES + PART_BYTES + SCR_BYTES + SCRK_BYTES + H_BYTES);

  pool_kernel<<<dim3(16, BATCH, L_LAYERS * 2), 256, 0, stream>>>(feat, h3, h5);
  quant_kernel<<<dim3(ROWS, L_LAYERS), 256, 0, stream>>>(feat, h3, h5, nf_all);
  gemm_max_kernel<<<TOTBLK, 256, 0, stream>>>(nf_all, part);
  reduce_topk_kernel<<<dim3(ROWS / 256, NCOMBO), 256, 0, stream>>>(part, scrk);
  sum_scores_kernel<<<ROWS / 256, 256, 0, stream>>>(scrk, scr);
  final_kernel<<<(BATCH * OH * OW) / 256 + BATCH, 256, 0, stream>>>(scr, out);
}

// Round 6
// 315.799 us; speedup vs baseline: 6.2579x; 1.0179x over previous
//
#include <hip/hip_runtime.h>
#include <stdint.h>

#define L_LAYERS 4
#define BATCH 8
#define PHH 24
#define PWW 24
#define PP (PHH*PWW)        // 576
#define DD 1024
#define ROWS (BATCH*PP)     // 4608
#define OH 336
#define OW 336
#define NTILES 72           // 4608/64  (64-col max groups)
#define TT 36               // 4608/128 (128x128 tiles per dim)
#define NPAIRS (TT*(TT+1)/2)  // 666 upper-triangle tiles
#define NCOMBO 12           // 3 radii x 4 layers
#define TOTBLK (NPAIRS*NCOMBO)   // 7992 = 8 * 999
#define PRESCALE 1024.0f    // fp8 quant prescale (power of 2, exact)
#define INV_PRESCALE2_X2 (1.f/524288.f)   // 2 / PRESCALE^2

typedef __attribute__((ext_vector_type(8))) int i32x8;
typedef __attribute__((ext_vector_type(4))) float f32x4;

// float -> bf16 round-to-nearest-even (raw bits)
__device__ __forceinline__ unsigned int f2bf(float f) {
  unsigned int u = __float_as_uint(f);
  return (u + 0x7FFFu + ((u >> 16) & 1u)) >> 16;
}

__device__ __forceinline__ float bflo(unsigned int w) {
  return __uint_as_float(w << 16);
}
__device__ __forceinline__ float bfhi(unsigned int w) {
  return __uint_as_float(w & 0xFFFF0000u);
}

// async global->LDS, 16B per lane. LDS dest is wave-uniform base + lane*16
// (base = first ACTIVE lane) -> never predicate individual lanes off.
__device__ __forceinline__ void async16(const void* g, void* l) {
  __builtin_amdgcn_global_load_lds(
      (const __attribute__((address_space(1))) void*)(size_t)(uintptr_t)g,
      (__attribute__((address_space(3))) void*)(uint32_t)(uintptr_t)l,
      16, 0, 0);
}

// ---------------------------------------------------------------------------
// Kernel 1: sliding-window pool, BOTH axes (reads feat exactly once).
// v3 (round 6): h3/h5 INTERLEAVED into one hh buffer as [h3pair, h5pair]
// uint2 per dim-pair -> 3 x 8-B stores per iteration instead of 6 x 4-B
// (half the store instructions, 512 B/wave-instr). Vertical 5-row window in
// registers (round-5 v2, verified). Arithmetic & rounding identical to v2
// -> bit-identical values, only storage layout changed.
// hh layout: [L][ROWS][DD] uints; uint at rowbase*DD + 2p   = h3 pair p,
//                              uint at rowbase*DD + 2p+1 = h5 pair p.
// ---------------------------------------------------------------------------
__global__ __launch_bounds__(256) void pool_kernel(
    const float* __restrict__ feat,      // [L][B][PP][DD]
    unsigned int* __restrict__ hh) {     // [L][ROWS][DD] interleaved bf16 pairs
  const int dch = blockIdx.x;            // 64-dim chunk
  const int b = blockIdx.y;
  const int l = blockIdx.z >> 1;
  const int half = blockIdx.z & 1;
  const int py0 = half * 12, py1 = py0 + 11;
  const int t = threadIdx.x;
  const int pxg = t >> 5;                // 0..7
  const int d2 = t & 31;                 // float2 index within 64-dim chunk

  __shared__ unsigned int v3p[24 * 32];  // 3 KB packed bf16 pairs
  __shared__ unsigned int v5p[24 * 32];  // 3 KB

  const float* fb = feat + ((size_t)l * BATCH + b) * PP * DD + dch * 64 + d2 * 2;

  const float2 z2 = {0.f, 0.f};
  // rolling window: w0..w4 = rows py-2 .. py+2 for this thread's 3 px
  float2 w0[3], w1[3], w2[3], w3[3], w4[3];
  #pragma unroll
  for (int i = 0; i < 3; ++i) { w0[i] = z2; w1[i] = z2; w2[i] = z2; w3[i] = z2; }

  // preload rows py0-2 .. py0+1 (OOB stays zero; conditions are block-uniform)
  if (py0 - 2 >= 0) {
    #pragma unroll
    for (int i = 0; i < 3; ++i) {
      int px = i * 8 + pxg;
      w0[i] = *(const float2*)(fb + (size_t)((py0 - 2) * PWW + px) * DD);
    }
  }
  if (py0 - 1 >= 0) {
    #pragma unroll
    for (int i = 0; i < 3; ++i) {
      int px = i * 8 + pxg;
      w1[i] = *(const float2*)(fb + (size_t)((py0 - 1) * PWW + px) * DD);
    }
  }
  #pragma unroll
  for (int i = 0; i < 3; ++i) {
    int px = i * 8 + pxg;
    w2[i] = *(const float2*)(fb + (size_t)(py0 * PWW + px) * DD);
    w3[i] = *(const float2*)(fb + (size_t)((py0 + 1) * PWW + px) * DD);
  }

  for (int py = py0; py <= py1; ++py) {
    // load row py+2 (block-uniform condition; zero when OOB)
    if (py + 2 < PHH) {
      #pragma unroll
      for (int i = 0; i < 3; ++i) {
        int px = i * 8 + pxg;
        w4[i] = *(const float2*)(fb + (size_t)((py + 2) * PWW + px) * DD);
      }
    } else {
      #pragma unroll
      for (int i = 0; i < 3; ++i) w4[i] = z2;
    }
    // vertical sums (same order as v2) -> packed bf16
    #pragma unroll
    for (int i = 0; i < 3; ++i) {
      int px = i * 8 + pxg;
      float s3x = w1[i].x + w2[i].x + w3[i].x;
      float s3y = w1[i].y + w2[i].y + w3[i].y;
      float s5x = w0[i].x + w1[i].x + w2[i].x + w3[i].x + w4[i].x;
      float s5y = w0[i].y + w1[i].y + w2[i].y + w3[i].y + w4[i].y;
      v3p[px * 32 + d2] = f2bf(s3x) | (f2bf(s3y) << 16);
      v5p[px * 32 + d2] = f2bf(s5x) | (f2bf(s5y) << 16);
    }
    __syncthreads();     // v-rows visible
    // horizontal phase: 3/5-col windows over packed rows -> global hh
    #pragma unroll
    for (int i = 0; i < 3; ++i) {
      int px = i * 8 + pxg;
      float h3x = 0.f, h3y = 0.f, h5x = 0.f, h5y = 0.f;
      #pragma unroll
      for (int dx = -2; dx <= 2; ++dx) {
        int xx = px + dx;
        if (xx < 0 || xx >= PWW) continue;
        unsigned int w5 = v5p[xx * 32 + d2];
        h5x += bflo(w5); h5y += bfhi(w5);
        if (dx >= -1 && dx <= 1) {
          unsigned int w3w = v3p[xx * 32 + d2];
          h3x += bflo(w3w); h3y += bfhi(w3w);
        }
      }
      // interleaved store: uint2{h3pair, h5pair}; index arithmetic identical
      // to the old ushort h3 index (uints here, ushorts before).
      const size_t idx =
          ((size_t)l * ROWS + b * PP + py * PWW + px) * DD + dch * 64 + d2 * 2;
      uint2 o;
      o.x = f2bf(h3x) | (f2bf(h3y) << 16);
      o.y = f2bf(h5x) | (f2bf(h5y) << 16);
      *(uint2*)&hh[idx] = o;
    }
    __syncthreads();     // reads done before next iteration's v-writes
    // shift window (static indexing only)
    #pragma unroll
    for (int i = 0; i < 3; ++i) {
      w0[i] = w1[i]; w1[i] = w2[i]; w2[i] = w3[i]; w3[i] = w4[i];
    }
  }
}

// ---------------------------------------------------------------------------
// Kernel 2: normalize + fp8(e4m3) quantize (x PRESCALE).
// v2 (round 6): h3/h5 read as ONE uint4 from interleaved hh (16 B/lane).
// Same index arithmetic (rowbase*DD + t*4), same reduction order ->
// bit-identical.
// ---------------------------------------------------------------------------
__global__ __launch_bounds__(256) void quant_kernel(
    const float* __restrict__ feat,
    const unsigned int* __restrict__ hh,     // [L][ROWS][DD] interleaved
    unsigned char* __restrict__ nf_all) {    // [NCOMBO][ROWS][DD] fp8
  const int row = blockIdx.x;
  const int l = blockIdx.y;
  const int t = threadIdx.x;
  const int lane = t & 63, w = t >> 6;
  const int d0 = t * 4;
  const size_t lro = ((size_t)l * ROWS + row) * DD + d0;

  float s1[4], s3[4], s5[4];
  {
    const float4 f = *(const float4*)(feat + lro);
    s1[0] = f.x; s1[1] = f.y; s1[2] = f.z; s1[3] = f.w;
  }
  {
    const uint4 hv = *(const uint4*)(hh + lro);
    s3[0] = bflo(hv.x); s3[1] = bfhi(hv.x);
    s5[0] = bflo(hv.y); s5[1] = bfhi(hv.y);
    s3[2] = bflo(hv.z); s3[3] = bfhi(hv.z);
    s5[2] = bflo(hv.w); s5[3] = bfhi(hv.w);
  }

  float q1 = 0.f, q3 = 0.f, q5 = 0.f;
  #pragma unroll
  for (int j = 0; j < 4; ++j) {
    q1 += s1[j]*s1[j]; q3 += s3[j]*s3[j]; q5 += s5[j]*s5[j];
  }
  #pragma unroll
  for (int off = 32; off > 0; off >>= 1) {
    q1 += __shfl_down(q1, off);
    q3 += __shfl_down(q3, off);
    q5 += __shfl_down(q5, off);
  }
  __shared__ float red[4][3];
  if (lane == 0) { red[w][0] = q1; red[w][1] = q3; red[w][2] = q5; }
  __syncthreads();
  const float rn1 = rsqrtf(red[0][0] + red[1][0] + red[2][0] + red[3][0]) * PRESCALE;
  const float rn3 = rsqrtf(red[0][1] + red[1][1] + red[2][1] + red[3][1]) * PRESCALE;
  const float rn5 = rsqrtf(red[0][2] + red[1][2] + red[2][2] + red[3][2]) * PRESCALE;

  const size_t ro = (size_t)row * DD + d0;
  unsigned int o;
  o = __builtin_amdgcn_cvt_pk_fp8_f32(s1[0]*rn1, s1[1]*rn1, 0, false);
  o = __builtin_amdgcn_cvt_pk_fp8_f32(s1[2]*rn1, s1[3]*rn1, o, true);
  *(unsigned int*)(nf_all + (size_t)(0*L_LAYERS + l) * ROWS * DD + ro) = o;
  o = __builtin_amdgcn_cvt_pk_fp8_f32(s3[0]*rn3, s3[1]*rn3, 0, false);
  o = __builtin_amdgcn_cvt_pk_fp8_f32(s3[2]*rn3, s3[3]*rn3, o, true);
  *(unsigned int*)(nf_all + (size_t)(1*L_LAYERS + l) * ROWS * DD + ro) = o;
  o = __builtin_amdgcn_cvt_pk_fp8_f32(s5[0]*rn5, s5[1]*rn5, 0, false);
  o = __builtin_amdgcn_cvt_pk_fp8_f32(s5[2]*rn5, s5[3]*rn5, o, true);
  *(unsigned int*)(nf_all + (size_t)(2*L_LAYERS + l) * ROWS * DD + ro) = o;
}

// ---------------------------------------------------------------------------
// Kernel 3: symmetric Gram GEMM, MX-fp8 (e4m3, unity E8M0 scales), K-tile=128.
// ROUND-0 VERIFIED VERSION (160 us steady, 84 VGPR, no scratch). At 1.70 PF
// this meets/exceeds the m148 reference ceiling (1628 TF) for the
// 128^2-tile 2-barrier structure with MX-fp8 -> structurally maxed.
//
// Session ledger on the 256x256/512-thread double-buffered variant
// (rounds 1-3, all FAILED identically): three structurally different
// encodings all compiled to VGPR_Count=128 with ~516 dwords/thread scratch
// round-trip (2.2 GB WRITE_SIZE, 3.2 GB FETCH, MfmaUtil 2.8%, 1780 us).
// DO NOT retry that structure without offline asm inspection showing the
// accumulator actually lands in AGPRs.
// ---------------------------------------------------------------------------
__global__ __launch_bounds__(256, 3) void gemm_max_kernel(
    const unsigned char* __restrict__ nf_all,   // [NCOMBO][ROWS][DD] fp8
    float* __restrict__ part) {                 // [NCOMBO][ROWS][NTILES]
  // XCD-aware swizzle (speed-only heuristic; every slot computed once)
  const int bid = blockIdx.x;
  const int slot = (bid & 7) * (TOTBLK / 8) + (bid >> 3);
  const int combo = slot / NPAIRS;
  int rem = slot % NPAIRS;
  int it = 0;
  while (rem >= TT - it) { rem -= TT - it; ++it; }
  const int jt = it + rem;
  const int row0 = it * 128;
  const int col0 = jt * 128;

  // dead-tile check: both tiles fully inside the same image -> never read
  {
    const bool inA = (row0 / PP) == ((row0 + 127) / PP);
    const bool inB = (col0 / PP) == ((col0 + 127) / PP);
    if (inA && inB && (row0 / PP) == (col0 / PP)) return;
  }

  __shared__ unsigned char As[128 * 128];
  __shared__ unsigned char Bs[128 * 128];

  const int t = threadIdx.x;
  const int lane = t & 63;
  const int wave = t >> 6;
  const int wm = wave >> 1;    // row half (64 rows)
  const int wn = wave & 1;     // col half (64 cols)

  const unsigned char* nf = nf_all + (size_t)combo * ROWS * DD;
  float* partialL = part + (size_t)combo * ROWS * NTILES;

  const f32x4 zero = {0.f, 0.f, 0.f, 0.f};
  f32x4 acc[4][4];
  #pragma unroll
  for (int m = 0; m < 4; ++m)
    #pragma unroll
    for (int n = 0; n < 4; ++n) acc[m][n] = zero;

  const unsigned char* gA = nf + (size_t)row0 * DD;
  const unsigned char* gB = nf + (size_t)col0 * DD;

  // lane-constant LDS fragment offset: 32B granule (2q) ^ (r15 & 6)
  const int r15 = lane & 15;
  const int loff = ((((lane >> 4) << 1) ^ (r15 & 6)) << 4);
  const unsigned char* Abase = As + (size_t)(wm * 64 + r15) * 128 + loff;
  const unsigned char* Bbase = Bs + (size_t)(wn * 64 + r15) * 128 + loff;

  for (int kt = 0; kt < DD / 128; ++kt) {
    const int k0 = kt * 128;
    // 128 rows x 128 B = 1024 16B-chunks per matrix; chunk c: row=c>>3,
    // slot j=c&7 holds global chunk j ^ (row&6)  (32B-granule XOR swizzle)
    #pragma unroll
    for (int i = 0; i < 4; ++i) {
      int c = i * 256 + t;
      int row = c >> 3, j = c & 7;
      int g = j ^ (row & 6);
      async16(gA + (size_t)row * DD + k0 + g * 16, &As[c * 16]);
    }
    #pragma unroll
    for (int i = 0; i < 4; ++i) {
      int c = i * 256 + t;
      int row = c >> 3, j = c & 7;
      int g = j ^ (row & 6);
      async16(gB + (size_t)row * DD + k0 + g * 16, &Bs[c * 16]);
    }
    __syncthreads();   // drains vmcnt (global_load_lds) + barrier

    const i32x8 a0 = *(const i32x8*)(Abase +    0);
    const i32x8 a1 = *(const i32x8*)(Abase + 2048);
    const i32x8 a2 = *(const i32x8*)(Abase + 4096);
    const i32x8 a3 = *(const i32x8*)(Abase + 6144);
    #pragma unroll
    for (int n = 0; n < 4; ++n) {
      const i32x8 bn = *(const i32x8*)(Bbase + n * 2048);
      acc[0][n] = __builtin_amdgcn_mfma_scale_f32_16x16x128_f8f6f4(
          a0, bn, acc[0][n], 0, 0, 0, 0x7F7F7F7F, 0, 0x7F7F7F7F);
      acc[1][n] = __builtin_amdgcn_mfma_scale_f32_16x16x128_f8f6f4(
          a1, bn, acc[1][n], 0, 0, 0, 0x7F7F7F7F, 0, 0x7F7F7F7F);
      acc[2][n] = __builtin_amdgcn_mfma_scale_f32_16x16x128_f8f6f4(
          a2, bn, acc[2][n], 0, 0, 0, 0x7F7F7F7F, 0, 0x7F7F7F7F);
      acc[3][n] = __builtin_amdgcn_mfma_scale_f32_16x16x128_f8f6f4(
          a3, bn, acc[3][n], 0, 0, 0, 0x7F7F7F7F, 0, 0x7F7F7F7F);
    }
    __syncthreads();
  }

  // C/D layout: col = lane&15, row = (lane>>4)*4 + reg (shape-determined)
  // Row-max over this wave's 64 cols (group 2*jt+wn).
  #pragma unroll
  for (int m = 0; m < 4; ++m) {
    #pragma unroll
    for (int g = 0; g < 4; ++g) {
      float v = fmaxf(fmaxf(acc[m][0][g], acc[m][1][g]),
                      fmaxf(acc[m][2][g], acc[m][3][g]));
      v = fmaxf(v, __shfl_xor(v, 1));
      v = fmaxf(v, __shfl_xor(v, 2));
      v = fmaxf(v, __shfl_xor(v, 4));
      v = fmaxf(v, __shfl_xor(v, 8));
      if ((lane & 15) == 0) {
        int row = row0 + wm * 64 + m * 16 + (lane >> 4) * 4 + g;
        partialL[(size_t)row * NTILES + 2 * jt + wn] = v;
      }
    }
  }
  // Col-max over this wave's 64 rows (group 2*it+wm), written transposed.
  if (it != jt) {
    #pragma unroll
    for (int n = 0; n < 4; ++n) {
      float v = -1e30f;
      #pragma unroll
      for (int m = 0; m < 4; ++m)
        #pragma unroll
        for (int g = 0; g < 4; ++g) v = fmaxf(v, acc[m][n][g]);
      v = fmaxf(v, __shfl_xor(v, 16));
      v = fmaxf(v, __shfl_xor(v, 32));
      if (lane < 16) {
        int col = col0 + wn * 64 + n * 16 + lane;
        partialL[(size_t)col * NTILES + 2 * it + wm] = v;
      }
    }
  }
}

// ---------------------------------------------------------------------------
// Kernel 4: per (row, combo): max over 9 q-groups per image, d-transform,
// top-2 smallest over c != b -> partial score. Grid (18, 12).
// v2 (round 6): row loaded as 18 float4 into a statically-indexed register
// array, then the IDENTICAL max/top-2 sequence (same op order).
// ---------------------------------------------------------------------------
__global__ __launch_bounds__(256) void reduce_topk_kernel(
    const float* __restrict__ part,      // [NCOMBO][ROWS][NTILES]
    float* __restrict__ scores_k) {      // [NCOMBO][ROWS]
  const int row = blockIdx.x * 256 + threadIdx.x;
  if (row >= ROWS) return;
  const int k = blockIdx.y;
  const int b = row / PP;
  const float* pr = part + ((size_t)k * ROWS + row) * NTILES;
  float arr[NTILES];
  #pragma unroll
  for (int j = 0; j < NTILES / 4; ++j)
    *(float4*)&arr[j * 4] = *(const float4*)(pr + j * 4);
  float d1 = 1e30f, d2 = 1e30f;
  #pragma unroll
  for (int c = 0; c < BATCH; ++c) {
    if (c == b) continue;
    float md = arr[c * 9];
    #pragma unroll
    for (int q = 1; q < 9; ++q) md = fmaxf(md, arr[c * 9 + q]);
    float d = sqrtf(fmaxf(2.f - md * INV_PRESCALE2_X2, 0.f));
    if (d < d1) { d2 = d1; d1 = d; }
    else if (d < d2) { d2 = d; }
  }
  scores_k[(size_t)k * ROWS + row] = 0.5f * (d1 + d2);
}

// Sum the 12 combo partials in ORIGINAL k order (bit-identical to v1).
__global__ __launch_bounds__(256) void sum_scores_kernel(
    const float* __restrict__ scores_k,  // [NCOMBO][ROWS]
    float* __restrict__ scores) {        // [ROWS]
  const int row = blockIdx.x * 256 + threadIdx.x;
  if (row >= ROWS) return;
  float sum = 0.f;
  #pragma unroll
  for (int k = 0; k < NCOMBO; ++k) sum += scores_k[(size_t)k * ROWS + row];
  scores[row] = sum;
}

// ---------------------------------------------------------------------------
// Kernel 5 (fused): blocks 0..3527 = bilinear (align_corners) 24x24 -> 336x336
// scaled 1/12; blocks 3528..3535 = scores_image[b] = max_p scores[b,p] / 12.
// ---------------------------------------------------------------------------
__global__ __launch_bounds__(256) void final_kernel(
    const float* __restrict__ scores, float* __restrict__ out) {
  const int bid = blockIdx.x;
  const int t = threadIdx.x;
  if (bid < (BATCH * OH * OW) / 256) {
    const int idx = bid * 256 + t;
    const int b = idx / (OH * OW);
    const int rem = idx % (OH * OW);
    const int y = rem / OW, x = rem % OW;
    const float sc = (float)(23.0 / 335.0);
    const float ys = y * sc, xs = x * sc;
    const int y0 = (int)floorf(ys), x0 = (int)floorf(xs);
    const float wy = ys - (float)y0, wx = xs - (float)x0;
    const int y1 = min(y0 + 1, PHH - 1), x1 = min(x0 + 1, PWW - 1);
    const float* sb = scores + b * PP;
    const float f00 = sb[y0 * PWW + x0], f01 = sb[y0 * PWW + x1];
    const float f10 = sb[y1 * PWW + x0], f11 = sb[y1 * PWW + x1];
    const float v = f00 * (1.f - wy) * (1.f - wx) + f01 * (1.f - wy) * wx +
                    f10 * wy * (1.f - wx) + f11 * wy * wx;
    out[8 + idx] = v * (1.f / 12.f);
  } else {
    const int b = bid - (BATCH * OH * OW) / 256;
    float m = -1e30f;
    for (int p = t; p < PP; p += 256) m = fmaxf(m, scores[b * PP + p]);
    #pragma unroll
    for (int off = 32; off > 0; off >>= 1) m = fmaxf(m, __shfl_down(m, off));
    __shared__ float red[4];
    if ((t & 63) == 0) red[t >> 6] = m;
    __syncthreads();
    if (t == 0)
      out[b] = fmaxf(fmaxf(red[0], red[1]), fmaxf(red[2], red[3])) * (1.f / 12.f);
  }
}

// ---------------------------------------------------------------------------
extern "C" void kernel_launch(void* const* d_in, const int* in_sizes, int n_in,
                              void* d_out, int out_size, void* d_ws, size_t ws_size,
                              hipStream_t stream) {
  const float* feat = (const float*)d_in[0];     // [4][8][576][1024] f32
  float* out = (float*)d_out;                    // [8] ++ [8][336][336]
  char* ws = (char*)d_ws;

  // workspace layout (~148.4 MB of ~302 MB)
  const size_t NF_BYTES   = (size_t)NCOMBO * ROWS * DD;            // 56,623,104 (fp8)
  const size_t PART_BYTES = (size_t)NCOMBO * ROWS * NTILES * 4;    // 15,925,248
  const size_t SCR_BYTES  = (size_t)ROWS * 4;                      //     18,432
  const size_t SCRK_BYTES = (size_t)NCOMBO * ROWS * 4;             //    221,184
  // hh: interleaved h3/h5 bf16 pairs, [L][ROWS][DD] uints = 75,497,472 B
  unsigned char*  nf_all = (unsigned char*)ws;
  float*          part   = (float*)(ws + NF_BYTES);
  float*          scr    = (float*)(ws + NF_BYTES + PART_BYTES);
  float*          scrk   = (float*)(ws + NF_BYTES + PART_BYTES + SCR_BYTES);
  unsigned int*   hh     = (unsigned int*)(ws + NF_BYTES + PART_BYTES + SCR_BYTES + SCRK_BYTES);

  pool_kernel<<<dim3(16, BATCH, L_LAYERS * 2), 256, 0, stream>>>(feat, hh);
  quant_kernel<<<dim3(ROWS, L_LAYERS), 256, 0, stream>>>(feat, hh, nf_all);
  gemm_max_kernel<<<TOTBLK, 256, 0, stream>>>(nf_all, part);
  reduce_topk_kernel<<<dim3(ROWS / 256, NCOMBO), 256, 0, stream>>>(part, scrk);
  sum_scores_kernel<<<ROWS / 256, 256, 0, stream>>>(scrk, scr);
  final_kernel<<<(BATCH * OH * OW) / 256 + BATCH, 256, 0, stream>>>(scr, out);
}

// Round 7
// 302.672 us; speedup vs baseline: 6.5293x; 1.0434x over previous
//
#include <hip/hip_runtime.h>
#include <stdint.h>

#define L_LAYERS 4
#define BATCH 8
#define PHH 24
#define PWW 24
#define PP (PHH*PWW)        // 576
#define DD 1024
#define ROWS (BATCH*PP)     // 4608
#define OH 336
#define OW 336
#define NTILES 72           // 4608/64  (64-col max groups)
#define TT 36               // 4608/128 (128x128 tiles per dim)
#define NPAIRS (TT*(TT+1)/2)  // 666 upper-triangle tiles
#define NCOMBO 12           // 3 radii x 4 layers
#define TOTBLK (NPAIRS*NCOMBO)   // 7992 = 8 * 999
#define PRESCALE 1024.0f    // fp8 quant prescale (power of 2, exact)
#define INV_PRESCALE2_X2 (1.f/524288.f)   // 2 / PRESCALE^2

typedef __attribute__((ext_vector_type(8))) int i32x8;
typedef __attribute__((ext_vector_type(4))) float f32x4;

// float -> bf16 round-to-nearest-even (raw bits)
__device__ __forceinline__ unsigned int f2bf(float f) {
  unsigned int u = __float_as_uint(f);
  return (u + 0x7FFFu + ((u >> 16) & 1u)) >> 16;
}

__device__ __forceinline__ float bflo(unsigned int w) {
  return __uint_as_float(w << 16);
}
__device__ __forceinline__ float bfhi(unsigned int w) {
  return __uint_as_float(w & 0xFFFF0000u);
}

// async global->LDS, 16B per lane. LDS dest is wave-uniform base + lane*16
// (base = first ACTIVE lane) -> never predicate individual lanes off.
__device__ __forceinline__ void async16(const void* g, void* l) {
  __builtin_amdgcn_global_load_lds(
      (const __attribute__((address_space(1))) void*)(size_t)(uintptr_t)g,
      (__attribute__((address_space(3))) void*)(uint32_t)(uintptr_t)l,
      16, 0, 0);
}

// ---------------------------------------------------------------------------
// Kernel 1: sliding-window pool, BOTH axes (reads feat exactly once).
// v4 (round 7): ONE barrier per iteration via parity double-buffered LDS
// row buffer (write vv[py&1]; the single barrier orders reuse two
// iterations out -- a wave can only reach the write of vv[p] at iter py+2
// after every wave passed the barrier of iter py+1, which is after all
// reads of vv[p] at iter py). v3p/v5p merged into one uint2 array:
// 1x8B LDS write + 5x8B reads per px instead of 2x4B + 8x4B (2-lane/bank
// aliasing = free). Vertical window in registers (round-5). Arithmetic,
// rounding, and order identical -> bit-identical hh.
// ---------------------------------------------------------------------------
__global__ __launch_bounds__(256) void pool_kernel(
    const float* __restrict__ feat,      // [L][B][PP][DD]
    unsigned int* __restrict__ hh) {     // [L][ROWS][DD] interleaved bf16 pairs
  const int dch = blockIdx.x;            // 64-dim chunk
  const int b = blockIdx.y;
  const int l = blockIdx.z >> 1;
  const int half = blockIdx.z & 1;
  const int py0 = half * 12, py1 = py0 + 11;
  const int t = threadIdx.x;
  const int pxg = t >> 5;                // 0..7
  const int d2 = t & 31;                 // float2 index within 64-dim chunk

  __shared__ uint2 vv[2][24 * 32];       // 12 KB: [parity][px*32+d2] = {v3,v5}

  const float* fb = feat + ((size_t)l * BATCH + b) * PP * DD + dch * 64 + d2 * 2;

  const float2 z2 = {0.f, 0.f};
  // rolling window: w0..w4 = rows py-2 .. py+2 for this thread's 3 px
  float2 w0[3], w1[3], w2[3], w3[3], w4[3];
  #pragma unroll
  for (int i = 0; i < 3; ++i) { w0[i] = z2; w1[i] = z2; w2[i] = z2; w3[i] = z2; }

  // preload rows py0-2 .. py0+1 (OOB stays zero; conditions are block-uniform)
  if (py0 - 2 >= 0) {
    #pragma unroll
    for (int i = 0; i < 3; ++i) {
      int px = i * 8 + pxg;
      w0[i] = *(const float2*)(fb + (size_t)((py0 - 2) * PWW + px) * DD);
    }
  }
  if (py0 - 1 >= 0) {
    #pragma unroll
    for (int i = 0; i < 3; ++i) {
      int px = i * 8 + pxg;
      w1[i] = *(const float2*)(fb + (size_t)((py0 - 1) * PWW + px) * DD);
    }
  }
  #pragma unroll
  for (int i = 0; i < 3; ++i) {
    int px = i * 8 + pxg;
    w2[i] = *(const float2*)(fb + (size_t)(py0 * PWW + px) * DD);
    w3[i] = *(const float2*)(fb + (size_t)((py0 + 1) * PWW + px) * DD);
  }

  for (int py = py0; py <= py1; ++py) {
    const int p = py & 1;
    // load row py+2 (block-uniform condition; zero when OOB)
    if (py + 2 < PHH) {
      #pragma unroll
      for (int i = 0; i < 3; ++i) {
        int px = i * 8 + pxg;
        w4[i] = *(const float2*)(fb + (size_t)((py + 2) * PWW + px) * DD);
      }
    } else {
      #pragma unroll
      for (int i = 0; i < 3; ++i) w4[i] = z2;
    }
    // vertical sums (same order as before) -> packed bf16 pairs
    #pragma unroll
    for (int i = 0; i < 3; ++i) {
      int px = i * 8 + pxg;
      float s3x = w1[i].x + w2[i].x + w3[i].x;
      float s3y = w1[i].y + w2[i].y + w3[i].y;
      float s5x = w0[i].x + w1[i].x + w2[i].x + w3[i].x + w4[i].x;
      float s5y = w0[i].y + w1[i].y + w2[i].y + w3[i].y + w4[i].y;
      uint2 u;
      u.x = f2bf(s3x) | (f2bf(s3y) << 16);
      u.y = f2bf(s5x) | (f2bf(s5y) << 16);
      vv[p][px * 32 + d2] = u;
    }
    __syncthreads();     // v-rows visible (single barrier per iteration)
    // horizontal phase: 3/5-col windows over packed rows -> global hh
    #pragma unroll
    for (int i = 0; i < 3; ++i) {
      int px = i * 8 + pxg;
      float h3x = 0.f, h3y = 0.f, h5x = 0.f, h5y = 0.f;
      #pragma unroll
      for (int dx = -2; dx <= 2; ++dx) {
        int xx = px + dx;
        if (xx < 0 || xx >= PWW) continue;
        const uint2 u = vv[p][xx * 32 + d2];
        h5x += bflo(u.y); h5y += bfhi(u.y);
        if (dx >= -1 && dx <= 1) {
          h3x += bflo(u.x); h3y += bfhi(u.x);
        }
      }
      const size_t idx =
          ((size_t)l * ROWS + b * PP + py * PWW + px) * DD + dch * 64 + d2 * 2;
      uint2 o;
      o.x = f2bf(h3x) | (f2bf(h3y) << 16);
      o.y = f2bf(h5x) | (f2bf(h5y) << 16);
      *(uint2*)&hh[idx] = o;
    }
    // no trailing barrier: next iteration writes vv[p^1]
    #pragma unroll
    for (int i = 0; i < 3; ++i) {
      w0[i] = w1[i]; w1[i] = w2[i]; w2[i] = w3[i]; w3[i] = w4[i];
    }
  }
}

// ---------------------------------------------------------------------------
// Kernel 2: normalize + fp8(e4m3) quantize (x PRESCALE).
// v3 (round 7): ONE WAVE PER ROW (4 rows/block, grid 1152x4): lane owns the
// same dim-quadruples as 4 old virtual threads (d0=(q*64+lane)*4), runs the
// IDENTICAL shfl_down tree per virtual wave (off=32..1), broadcasts lane 0,
// accumulates q=0..3 in the old red[0..3] left-assoc order -> bit-identical
// rn. No LDS, no barrier, 8x16B loads issued up front (4x load ILP).
// ---------------------------------------------------------------------------
__global__ __launch_bounds__(256) void quant_kernel(
    const float* __restrict__ feat,
    const unsigned int* __restrict__ hh,     // [L][ROWS][DD] interleaved
    unsigned char* __restrict__ nf_all) {    // [NCOMBO][ROWS][DD] fp8
  const int t = threadIdx.x;
  const int lane = t & 63;
  const int wv = t >> 6;                     // wave index in block = row offset
  const int row = blockIdx.x * 4 + wv;
  const int l = blockIdx.y;
  const size_t rowbase = ((size_t)l * ROWS + row) * DD;

  float s1[16], s3[16], s5[16];
  #pragma unroll
  for (int q = 0; q < 4; ++q) {
    const int d0 = (q * 64 + lane) * 4;
    const float4 f = *(const float4*)(feat + rowbase + d0);
    s1[q*4+0] = f.x; s1[q*4+1] = f.y; s1[q*4+2] = f.z; s1[q*4+3] = f.w;
    const uint4 hv = *(const uint4*)(hh + rowbase + d0);
    s3[q*4+0] = bflo(hv.x); s3[q*4+1] = bfhi(hv.x);
    s5[q*4+0] = bflo(hv.y); s5[q*4+1] = bfhi(hv.y);
    s3[q*4+2] = bflo(hv.z); s3[q*4+3] = bfhi(hv.z);
    s5[q*4+2] = bflo(hv.w); s5[q*4+3] = bfhi(hv.w);
  }

  float r1 = 0.f, r3 = 0.f, r5 = 0.f;
  #pragma unroll
  for (int q = 0; q < 4; ++q) {
    float q1 = 0.f, q3 = 0.f, q5 = 0.f;
    #pragma unroll
    for (int j = 0; j < 4; ++j) {
      q1 += s1[q*4+j]*s1[q*4+j];
      q3 += s3[q*4+j]*s3[q*4+j];
      q5 += s5[q*4+j]*s5[q*4+j];
    }
    #pragma unroll
    for (int off = 32; off > 0; off >>= 1) {
      q1 += __shfl_down(q1, off);
      q3 += __shfl_down(q3, off);
      q5 += __shfl_down(q5, off);
    }
    // lane 0 now holds the exact virtual-wave-q tree sum; broadcast
    q1 = __shfl(q1, 0); q3 = __shfl(q3, 0); q5 = __shfl(q5, 0);
    r1 += q1; r3 += q3; r5 += q5;       // ((q0+q1)+q2)+q3 == old red order
  }
  const float rn1 = rsqrtf(r1) * PRESCALE;
  const float rn3 = rsqrtf(r3) * PRESCALE;
  const float rn5 = rsqrtf(r5) * PRESCALE;

  const size_t ro = (size_t)row * DD;
  #pragma unroll
  for (int q = 0; q < 4; ++q) {
    const int d0 = (q * 64 + lane) * 4;
    unsigned int o;
    o = __builtin_amdgcn_cvt_pk_fp8_f32(s1[q*4+0]*rn1, s1[q*4+1]*rn1, 0, false);
    o = __builtin_amdgcn_cvt_pk_fp8_f32(s1[q*4+2]*rn1, s1[q*4+3]*rn1, o, true);
    *(unsigned int*)(nf_all + (size_t)(0*L_LAYERS + l) * ROWS * DD + ro + d0) = o;
    o = __builtin_amdgcn_cvt_pk_fp8_f32(s3[q*4+0]*rn3, s3[q*4+1]*rn3, 0, false);
    o = __builtin_amdgcn_cvt_pk_fp8_f32(s3[q*4+2]*rn3, s3[q*4+3]*rn3, o, true);
    *(unsigned int*)(nf_all + (size_t)(1*L_LAYERS + l) * ROWS * DD + ro + d0) = o;
    o = __builtin_amdgcn_cvt_pk_fp8_f32(s5[q*4+0]*rn5, s5[q*4+1]*rn5, 0, false);
    o = __builtin_amdgcn_cvt_pk_fp8_f32(s5[q*4+2]*rn5, s5[q*4+3]*rn5, o, true);
    *(unsigned int*)(nf_all + (size_t)(2*L_LAYERS + l) * ROWS * DD + ro + d0) = o;
  }
}

// ---------------------------------------------------------------------------
// Kernel 3: symmetric Gram GEMM, MX-fp8 (e4m3, unity E8M0 scales), K-tile=128.
// ROUND-0 VERIFIED VERSION (160 us steady, 84 VGPR, no scratch). At 1.70 PF
// this meets/exceeds the m148 reference ceiling (1628 TF) for the
// 128^2-tile 2-barrier structure with MX-fp8 -> structurally maxed.
//
// Session ledger on the 256x256/512-thread double-buffered variant
// (rounds 1-3, all FAILED identically): three structurally different
// encodings all compiled to VGPR_Count=128 with ~516 dwords/thread scratch
// round-trip (2.2 GB WRITE_SIZE, 3.2 GB FETCH, MfmaUtil 2.8%, 1780 us).
// DO NOT retry that structure without offline asm inspection showing the
// accumulator actually lands in AGPRs.
// ---------------------------------------------------------------------------
__global__ __launch_bounds__(256, 3) void gemm_max_kernel(
    const unsigned char* __restrict__ nf_all,   // [NCOMBO][ROWS][DD] fp8
    float* __restrict__ part) {                 // [NCOMBO][ROWS][NTILES]
  // XCD-aware swizzle (speed-only heuristic; every slot computed once)
  const int bid = blockIdx.x;
  const int slot = (bid & 7) * (TOTBLK / 8) + (bid >> 3);
  const int combo = slot / NPAIRS;
  int rem = slot % NPAIRS;
  int it = 0;
  while (rem >= TT - it) { rem -= TT - it; ++it; }
  const int jt = it + rem;
  const int row0 = it * 128;
  const int col0 = jt * 128;

  // dead-tile check: both tiles fully inside the same image -> never read
  {
    const bool inA = (row0 / PP) == ((row0 + 127) / PP);
    const bool inB = (col0 / PP) == ((col0 + 127) / PP);
    if (inA && inB && (row0 / PP) == (col0 / PP)) return;
  }

  __shared__ unsigned char As[128 * 128];
  __shared__ unsigned char Bs[128 * 128];

  const int t = threadIdx.x;
  const int lane = t & 63;
  const int wave = t >> 6;
  const int wm = wave >> 1;    // row half (64 rows)
  const int wn = wave & 1;     // col half (64 cols)

  const unsigned char* nf = nf_all + (size_t)combo * ROWS * DD;
  float* partialL = part + (size_t)combo * ROWS * NTILES;

  const f32x4 zero = {0.f, 0.f, 0.f, 0.f};
  f32x4 acc[4][4];
  #pragma unroll
  for (int m = 0; m < 4; ++m)
    #pragma unroll
    for (int n = 0; n < 4; ++n) acc[m][n] = zero;

  const unsigned char* gA = nf + (size_t)row0 * DD;
  const unsigned char* gB = nf + (size_t)col0 * DD;

  // lane-constant LDS fragment offset: 32B granule (2q) ^ (r15 & 6)
  const int r15 = lane & 15;
  const int loff = ((((lane >> 4) << 1) ^ (r15 & 6)) << 4);
  const unsigned char* Abase = As + (size_t)(wm * 64 + r15) * 128 + loff;
  const unsigned char* Bbase = Bs + (size_t)(wn * 64 + r15) * 128 + loff;

  for (int kt = 0; kt < DD / 128; ++kt) {
    const int k0 = kt * 128;
    // 128 rows x 128 B = 1024 16B-chunks per matrix; chunk c: row=c>>3,
    // slot j=c&7 holds global chunk j ^ (row&6)  (32B-granule XOR swizzle)
    #pragma unroll
    for (int i = 0; i < 4; ++i) {
      int c = i * 256 + t;
      int row = c >> 3, j = c & 7;
      int g = j ^ (row & 6);
      async16(gA + (size_t)row * DD + k0 + g * 16, &As[c * 16]);
    }
    #pragma unroll
    for (int i = 0; i < 4; ++i) {
      int c = i * 256 + t;
      int row = c >> 3, j = c & 7;
      int g = j ^ (row & 6);
      async16(gB + (size_t)row * DD + k0 + g * 16, &Bs[c * 16]);
    }
    __syncthreads();   // drains vmcnt (global_load_lds) + barrier

    const i32x8 a0 = *(const i32x8*)(Abase +    0);
    const i32x8 a1 = *(const i32x8*)(Abase + 2048);
    const i32x8 a2 = *(const i32x8*)(Abase + 4096);
    const i32x8 a3 = *(const i32x8*)(Abase + 6144);
    #pragma unroll
    for (int n = 0; n < 4; ++n) {
      const i32x8 bn = *(const i32x8*)(Bbase + n * 2048);
      acc[0][n] = __builtin_amdgcn_mfma_scale_f32_16x16x128_f8f6f4(
          a0, bn, acc[0][n], 0, 0, 0, 0x7F7F7F7F, 0, 0x7F7F7F7F);
      acc[1][n] = __builtin_amdgcn_mfma_scale_f32_16x16x128_f8f6f4(
          a1, bn, acc[1][n], 0, 0, 0, 0x7F7F7F7F, 0, 0x7F7F7F7F);
      acc[2][n] = __builtin_amdgcn_mfma_scale_f32_16x16x128_f8f6f4(
          a2, bn, acc[2][n], 0, 0, 0, 0x7F7F7F7F, 0, 0x7F7F7F7F);
      acc[3][n] = __builtin_amdgcn_mfma_scale_f32_16x16x128_f8f6f4(
          a3, bn, acc[3][n], 0, 0, 0, 0x7F7F7F7F, 0, 0x7F7F7F7F);
    }
    __syncthreads();
  }

  // C/D layout: col = lane&15, row = (lane>>4)*4 + reg (shape-determined)
  // Row-max over this wave's 64 cols (group 2*jt+wn).
  #pragma unroll
  for (int m = 0; m < 4; ++m) {
    #pragma unroll
    for (int g = 0; g < 4; ++g) {
      float v = fmaxf(fmaxf(acc[m][0][g], acc[m][1][g]),
                      fmaxf(acc[m][2][g], acc[m][3][g]));
      v = fmaxf(v, __shfl_xor(v, 1));
      v = fmaxf(v, __shfl_xor(v, 2));
      v = fmaxf(v, __shfl_xor(v, 4));
      v = fmaxf(v, __shfl_xor(v, 8));
      if ((lane & 15) == 0) {
        int row = row0 + wm * 64 + m * 16 + (lane >> 4) * 4 + g;
        partialL[(size_t)row * NTILES + 2 * jt + wn] = v;
      }
    }
  }
  // Col-max over this wave's 64 rows (group 2*it+wm), written transposed.
  if (it != jt) {
    #pragma unroll
    for (int n = 0; n < 4; ++n) {
      float v = -1e30f;
      #pragma unroll
      for (int m = 0; m < 4; ++m)
        #pragma unroll
        for (int g = 0; g < 4; ++g) v = fmaxf(v, acc[m][n][g]);
      v = fmaxf(v, __shfl_xor(v, 16));
      v = fmaxf(v, __shfl_xor(v, 32));
      if (lane < 16) {
        int col = col0 + wn * 64 + n * 16 + lane;
        partialL[(size_t)col * NTILES + 2 * it + wm] = v;
      }
    }
  }
}

// ---------------------------------------------------------------------------
// Kernel 4: per (row, combo): max over 9 q-groups per image, d-transform,
// top-2 smallest over c != b -> partial score. Grid (18, 12).
// Row loaded as 18 float4 into statically-indexed registers, then the
// IDENTICAL max/top-2 sequence (same op order).
// ---------------------------------------------------------------------------
__global__ __launch_bounds__(256) void reduce_topk_kernel(
    const float* __restrict__ part,      // [NCOMBO][ROWS][NTILES]
    float* __restrict__ scores_k) {      // [NCOMBO][ROWS]
  const int row = blockIdx.x * 256 + threadIdx.x;
  if (row >= ROWS) return;
  const int k = blockIdx.y;
  const int b = row / PP;
  const float* pr = part + ((size_t)k * ROWS + row) * NTILES;
  float arr[NTILES];
  #pragma unroll
  for (int j = 0; j < NTILES / 4; ++j)
    *(float4*)&arr[j * 4] = *(const float4*)(pr + j * 4);
  float d1 = 1e30f, d2 = 1e30f;
  #pragma unroll
  for (int c = 0; c < BATCH; ++c) {
    if (c == b) continue;
    float md = arr[c * 9];
    #pragma unroll
    for (int q = 1; q < 9; ++q) md = fmaxf(md, arr[c * 9 + q]);
    float d = sqrtf(fmaxf(2.f - md * INV_PRESCALE2_X2, 0.f));
    if (d < d1) { d2 = d1; d1 = d; }
    else if (d < d2) { d2 = d; }
  }
  scores_k[(size_t)k * ROWS + row] = 0.5f * (d1 + d2);
}

// Sum the 12 combo partials in ORIGINAL k order (bit-identical to v1).
__global__ __launch_bounds__(256) void sum_scores_kernel(
    const float* __restrict__ scores_k,  // [NCOMBO][ROWS]
    float* __restrict__ scores) {        // [ROWS]
  const int row = blockIdx.x * 256 + threadIdx.x;
  if (row >= ROWS) return;
  float sum = 0.f;
  #pragma unroll
  for (int k = 0; k < NCOMBO; ++k) sum += scores_k[(size_t)k * ROWS + row];
  scores[row] = sum;
}

// ---------------------------------------------------------------------------
// Kernel 5 (fused): blocks 0..3527 = bilinear (align_corners) 24x24 -> 336x336
// scaled 1/12; blocks 3528..3535 = scores_image[b] = max_p scores[b,p] / 12.
// ---------------------------------------------------------------------------
__global__ __launch_bounds__(256) void final_kernel(
    const float* __restrict__ scores, float* __restrict__ out) {
  const int bid = blockIdx.x;
  const int t = threadIdx.x;
  if (bid < (BATCH * OH * OW) / 256) {
    const int idx = bid * 256 + t;
    const int b = idx / (OH * OW);
    const int rem = idx % (OH * OW);
    const int y = rem / OW, x = rem % OW;
    const float sc = (float)(23.0 / 335.0);
    const float ys = y * sc, xs = x * sc;
    const int y0 = (int)floorf(ys), x0 = (int)floorf(xs);
    const float wy = ys - (float)y0, wx = xs - (float)x0;
    const int y1 = min(y0 + 1, PHH - 1), x1 = min(x0 + 1, PWW - 1);
    const float* sb = scores + b * PP;
    const float f00 = sb[y0 * PWW + x0], f01 = sb[y0 * PWW + x1];
    const float f10 = sb[y1 * PWW + x0], f11 = sb[y1 * PWW + x1];
    const float v = f00 * (1.f - wy) * (1.f - wx) + f01 * (1.f - wy) * wx +
                    f10 * wy * (1.f - wx) + f11 * wy * wx;
    out[8 + idx] = v * (1.f / 12.f);
  } else {
    const int b = bid - (BATCH * OH * OW) / 256;
    float m = -1e30f;
    for (int p = t; p < PP; p += 256) m = fmaxf(m, scores[b * PP + p]);
    #pragma unroll
    for (int off = 32; off > 0; off >>= 1) m = fmaxf(m, __shfl_down(m, off));
    __shared__ float red[4];
    if ((t & 63) == 0) red[t >> 6] = m;
    __syncthreads();
    if (t == 0)
      out[b] = fmaxf(fmaxf(red[0], red[1]), fmaxf(red[2], red[3])) * (1.f / 12.f);
  }
}

// ---------------------------------------------------------------------------
extern "C" void kernel_launch(void* const* d_in, const int* in_sizes, int n_in,
                              void* d_out, int out_size, void* d_ws, size_t ws_size,
                              hipStream_t stream) {
  const float* feat = (const float*)d_in[0];     // [4][8][576][1024] f32
  float* out = (float*)d_out;                    // [8] ++ [8][336][336]
  char* ws = (char*)d_ws;

  // workspace layout (~148.4 MB of ~302 MB)
  const size_t NF_BYTES   = (size_t)NCOMBO * ROWS * DD;            // 56,623,104 (fp8)
  const size_t PART_BYTES = (size_t)NCOMBO * ROWS * NTILES * 4;    // 15,925,248
  const size_t SCR_BYTES  = (size_t)ROWS * 4;                      //     18,432
  const size_t SCRK_BYTES = (size_t)NCOMBO * ROWS * 4;             //    221,184
  // hh: interleaved h3/h5 bf16 pairs, [L][ROWS][DD] uints = 75,497,472 B
  unsigned char*  nf_all = (unsigned char*)ws;
  float*          part   = (float*)(ws + NF_BYTES);
  float*          scr    = (float*)(ws + NF_BYTES + PART_BYTES);
  float*          scrk   = (float*)(ws + NF_BYTES + PART_BYTES + SCR_BYTES);
  unsigned int*   hh     = (unsigned int*)(ws + NF_BYTES + PART_BYTES + SCR_BYTES + SCRK_BYTES);

  pool_kernel<<<dim3(16, BATCH, L_LAYERS * 2), 256, 0, stream>>>(feat, hh);
  quant_kernel<<<dim3(ROWS / 4, L_LAYERS), 256, 0, stream>>>(feat, hh, nf_all);
  gemm_max_kernel<<<TOTBLK, 256, 0, stream>>>(nf_all, part);
  reduce_topk_kernel<<<dim3(ROWS / 256, NCOMBO), 256, 0, stream>>>(part, scrk);
  sum_scores_kernel<<<ROWS / 256, 256, 0, stream>>>(scrk, scr);
  final_kernel<<<(BATCH * OH * OW) / 256 + BATCH, 256, 0, stream>>>(scr, out);
}